// Round 6
// baseline (3962.286 us; speedup 1.0000x reference)
//
#include <hip/hip_runtime.h>

// StructLNN: LN(67) -> Linear(67,256)+LN+SiLU -> CfC scan (2048 steps) -> LN head -> [B,S,1]
//   prep: repack weights (W_x^T bf16 for GEMM, W_h int8 per-column quant in scan-thread layout)
//   k2 feat_kernel: input LN + MFMA proj + LN + SiLU -> feat bf16
//   k3 gemm_kernel: pre = feat @ W_x^T + bias4 (bf16 MFMA)
//   k4 scan_kernel: 1 WG/batch, 512 thr; thread owns h-index j0 for all 4 gates, k-half hf.
//      128 weight dwords/thread held in PHYSICAL AGPRs a0..a127 (v_accvgpr_write/read with
//      literal register names + clobbers). r2-r5 proved the RA spills/sinks any compiler-
//      managed storage (VGPR_Count stuck at 88-96, 256KB/WG/step re-streamed at ~27TB/s =
//      L2-bound 625us). Physical regs are outside the allocator: cannot spill.
//   k5 head_kernel: folded LN+head over hseq (memory-bound).

typedef __bf16 bf16x8 __attribute__((ext_vector_type(8)));
typedef float f32x4 __attribute__((ext_vector_type(4)));

#define DEVFN static __device__ __forceinline__

DEVFN float bf2f(unsigned short u){ return __uint_as_float(((unsigned)u) << 16); }
DEVFN unsigned short f2bf(float f){
  unsigned x = __float_as_uint(f);
  return (unsigned short)((x + 0x7FFFu + ((x >> 16) & 1u)) >> 16);
}
DEVFN float sigm(float x){ return 1.f / (1.f + __expf(-x)); }
DEVFN float tanh_f(float x){ return 1.f - 2.f / (__expf(2.f * x) + 1.f); }

#if __has_builtin(__builtin_amdgcn_sdot4)
DEVFN int dot4i8(int a, int b, int c){ return __builtin_amdgcn_sdot4(a, b, c, false); }
#else
DEVFN int dot4i8(int a, int b, int c){
  c += (int)(signed char)(a & 0xff)        * (int)(signed char)(b & 0xff);
  c += (int)(signed char)((a >> 8) & 0xff) * (int)(signed char)((b >> 8) & 0xff);
  c += (int)(signed char)((a >> 16) & 0xff)* (int)(signed char)((b >> 16) & 0xff);
  c += (a >> 24) * (b >> 24);
  return c;
}
#endif

#define GLD_LDS16(g, l) \
  __builtin_amdgcn_global_load_lds((const __attribute__((address_space(1))) void*)(g), \
                                   (__attribute__((address_space(3))) void*)(l), 16, 0, 0)

static constexpr int BB = 128;
static constexpr int SS = 2048;
static constexpr int DD = 67;

// ws layout (bytes)
static constexpr size_t OFF_WXT   = 0;         // bf16 [1024][256]  W_x^T (x-part of 4 mats)
static constexpr size_t OFF_WQ    = 524288;    // i8   [512 thr][4 gates][128]  W_h^T quant, scan layout
static constexpr size_t OFF_SW    = 786432;    // f32  [1024] per-column scales
static constexpr size_t OFF_BIAS4 = 790528;    // f32  [1024] concat(b_ff1,b_ff2,b_ta,b_tb)
static constexpr size_t OFF_PWT   = 794624;    // bf16 [256][96] proj_W^T zero-padded
static constexpr size_t OFF_GW    = 843776;    // f32  [256] head_g*head_W
static constexpr size_t OFF_SCAL  = 844800;    // f32  [2]: S_gW, S_bW+head_bias
static constexpr size_t OFF_HST   = 845824;    // i32  [128][64] persisted packed-int8 h
static constexpr size_t OFF_FEAT  = 878592;    // bf16 [B*C][256] (feat, then reused as hseq)

// ---------------------------------------------------------------- prep
__global__ __launch_bounds__(256) void prep_kernel(
    const float* __restrict__ proj_W,
    const float* __restrict__ W_ff1, const float* __restrict__ b_ff1,
    const float* __restrict__ W_ff2, const float* __restrict__ b_ff2,
    const float* __restrict__ W_ta,  const float* __restrict__ b_ta,
    const float* __restrict__ W_tb,  const float* __restrict__ b_tb,
    const float* __restrict__ head_g, const float* __restrict__ head_b,
    const float* __restrict__ head_W, const float* __restrict__ head_bias,
    unsigned short* __restrict__ WxT, signed char* __restrict__ wq,
    float* __restrict__ sw, float* __restrict__ bias4,
    unsigned short* __restrict__ PWT, float* __restrict__ gW, float* __restrict__ scal)
{
  __shared__ float red[8];
  int bid = blockIdx.x, t = threadIdx.x;
  int wv = t >> 6, ln = t & 63;
  if (bid < 1024) {
    int J = bid, col = J & 255, which = J >> 8;
    const float* Wsrc = which == 0 ? W_ff1 : which == 1 ? W_ff2 : which == 2 ? W_ta : W_tb;
    const float* bsrc = which == 0 ? b_ff1 : which == 1 ? b_ff2 : which == 2 ? b_ta : b_tb;
    float w = Wsrc[t * 256 + col];          // x-part rows 0..255
    WxT[J * 256 + t] = f2bf(w);
    if (t == 0) bias4[J] = bsrc[col];
  } else if (bid < 2048) {
    int J = bid - 1024, col = J & 255, which = J >> 8;
    const float* Wsrc = which == 0 ? W_ff1 : which == 1 ? W_ff2 : which == 2 ? W_ta : W_tb;
    float w = Wsrc[(256 + t) * 256 + col];  // h-part rows 256..511, k = t
    float a = fabsf(w);
    for (int m = 32; m >= 1; m >>= 1) a = fmaxf(a, __shfl_xor(a, m, 64));
    if (ln == 0) red[wv] = a;
    __syncthreads();
    a = fmaxf(fmaxf(red[0], red[1]), fmaxf(red[2], red[3]));
    float scale = (a > 0.f) ? a * (1.f / 127.f) : 1.f;
    int q = (int)rintf(w / scale);
    q = q > 127 ? 127 : (q < -127 ? -127 : q);
    // scan-thread layout: thread st owns (j0=col, k-half hf=t>>7), gate=which, ki=t&127
    int st = (col >> 5) * 64 + (t >> 7) * 32 + (col & 31);
    wq[(size_t)st * 512 + which * 128 + (t & 127)] = (signed char)q;
    if (t == 0) sw[J] = scale;
  } else {
    for (int idx = t; idx < 256 * 96; idx += 256) {
      int j = idx / 96, d = idx % 96;
      float v = (d < DD) ? proj_W[d * 256 + j] : 0.f;
      PWT[idx] = f2bf(v);
    }
    float gw = head_g[t] * head_W[t];
    gW[t] = gw;
    float bw = head_b[t] * head_W[t];
    float s1 = gw, s2 = bw;
    for (int m = 32; m >= 1; m >>= 1) { s1 += __shfl_xor(s1, m, 64); s2 += __shfl_xor(s2, m, 64); }
    if (ln == 0) { red[wv] = s1; red[4 + wv] = s2; }
    __syncthreads();
    if (t == 0) {
      scal[0] = red[0] + red[1] + red[2] + red[3];
      scal[1] = red[4] + red[5] + red[6] + red[7] + head_bias[0];
    }
  }
}

// ---------------------------------------------------------------- k2: x -> feat
__global__ __launch_bounds__(512) void feat_kernel(
    const float* __restrict__ x, const float* __restrict__ ln_in_g, const float* __restrict__ ln_in_b,
    const float* __restrict__ proj_b, const float* __restrict__ ln_p_g, const float* __restrict__ ln_p_b,
    const unsigned short* __restrict__ PWT, unsigned short* __restrict__ feat,
    int s0, int C, int cshift)
{
  __shared__ __align__(16) unsigned short XA[64 * 104];
  __shared__ __align__(16) unsigned short XB[256 * 96];
  __shared__ float partS[64][4], partQ[64][4], statM[64], statI[64];
  int tid = threadIdx.x, w = tid >> 6, lane = tid & 63;
  int r0 = blockIdx.x * 64;

  {
    float g1v = (lane < 67) ? ln_in_g[lane] : 0.f;
    float b1v = (lane < 67) ? ln_in_b[lane] : 0.f;
    float g2v = (lane < 3) ? ln_in_g[64 + lane] : 0.f;
    float b2v = (lane < 3) ? ln_in_b[64 + lane] : 0.f;
    for (int i = 0; i < 8; ++i) {
      int rl = w * 8 + i;
      int r = r0 + rl;
      int bb = r >> cshift, cs = r & (C - 1);
      const float* xr = x + (size_t)(bb * SS + s0 + cs) * DD;
      float v0 = (lane < 67) ? xr[lane] : 0.f;
      float v1 = (lane < 3) ? xr[64 + lane] : 0.f;
      float s = v0 + v1, q = v0 * v0 + v1 * v1;
      for (int m = 32; m >= 1; m >>= 1) { s += __shfl_xor(s, m, 64); q += __shfl_xor(q, m, 64); }
      float mean = s * (1.f / 67.f);
      float var = q * (1.f / 67.f) - mean * mean;
      float inv = rsqrtf(var + 1e-5f);
      float xn0 = (v0 - mean) * inv * g1v + b1v;
      float xn1 = (v1 - mean) * inv * g2v + b2v;
      XA[rl * 104 + lane] = (lane < 67) ? f2bf(xn0) : (unsigned short)0;
      if (lane < 40) XA[rl * 104 + 64 + lane] = (lane < 3) ? f2bf(xn1) : (unsigned short)0;
    }
  }
  {
    const unsigned int* src = (const unsigned int*)PWT;
    unsigned int* dst = (unsigned int*)XB;
    for (int idx = tid; idx < 256 * 48; idx += 512) dst[idx] = src[idx];
  }
  __syncthreads();

  int wm = w >> 2, wn = w & 3;
  f32x4 acc[2][4];
  #pragma unroll
  for (int mt = 0; mt < 2; ++mt)
    #pragma unroll
    for (int nt = 0; nt < 4; ++nt) acc[mt][nt] = (f32x4){0.f, 0.f, 0.f, 0.f};
  #pragma unroll
  for (int ks = 0; ks < 3; ++ks) {
    int k = ks * 32 + (lane >> 4) * 8;
    bf16x8 a[2], b[4];
    #pragma unroll
    for (int mt = 0; mt < 2; ++mt) {
      int row = wm * 32 + mt * 16 + (lane & 15);
      a[mt] = *reinterpret_cast<const bf16x8*>(&XA[row * 104 + k]);
    }
    #pragma unroll
    for (int nt = 0; nt < 4; ++nt) {
      int col = wn * 64 + nt * 16 + (lane & 15);
      b[nt] = *reinterpret_cast<const bf16x8*>(&XB[col * 96 + k]);
    }
    #pragma unroll
    for (int mt = 0; mt < 2; ++mt)
      #pragma unroll
      for (int nt = 0; nt < 4; ++nt)
        acc[mt][nt] = __builtin_amdgcn_mfma_f32_16x16x32_bf16(a[mt], b[nt], acc[mt][nt], 0, 0, 0);
  }
  #pragma unroll
  for (int nt = 0; nt < 4; ++nt) {
    int col = wn * 64 + nt * 16 + (lane & 15);
    float pb = proj_b[col];
    #pragma unroll
    for (int mt = 0; mt < 2; ++mt)
      #pragma unroll
      for (int r = 0; r < 4; ++r) acc[mt][nt][r] += pb;
  }
  #pragma unroll
  for (int mt = 0; mt < 2; ++mt) {
    #pragma unroll
    for (int r = 0; r < 4; ++r) {
      float s = 0.f, q = 0.f;
      #pragma unroll
      for (int nt = 0; nt < 4; ++nt) { float v = acc[mt][nt][r]; s += v; q += v * v; }
      for (int m = 1; m < 16; m <<= 1) { s += __shfl_xor(s, m, 16); q += __shfl_xor(q, m, 16); }
      if ((lane & 15) == 0) {
        int row = wm * 32 + mt * 16 + (lane >> 4) * 4 + r;
        partS[row][wn] = s; partQ[row][wn] = q;
      }
    }
  }
  __syncthreads();
  if (tid < 64) {
    float s = partS[tid][0] + partS[tid][1] + partS[tid][2] + partS[tid][3];
    float q = partQ[tid][0] + partQ[tid][1] + partQ[tid][2] + partQ[tid][3];
    float mean = s * (1.f / 256.f);
    float var = q * (1.f / 256.f) - mean * mean;
    statM[tid] = mean; statI[tid] = rsqrtf(var + 1e-5f);
  }
  __syncthreads();
  #pragma unroll
  for (int nt = 0; nt < 4; ++nt) {
    int col = wn * 64 + nt * 16 + (lane & 15);
    float gc = ln_p_g[col], bc = ln_p_b[col];
    #pragma unroll
    for (int mt = 0; mt < 2; ++mt)
      #pragma unroll
      for (int r = 0; r < 4; ++r) {
        int row = wm * 32 + mt * 16 + (lane >> 4) * 4 + r;
        float v = acc[mt][nt][r];
        float y = (v - statM[row]) * statI[row] * gc + bc;
        float sl = y * sigm(y);
        feat[(size_t)(r0 + row) * 256 + col] = f2bf(sl);
      }
  }
}

// ---------------------------------------------------------------- k3: pre = feat @ WxT + bias4
__global__ __launch_bounds__(256, 2) void gemm_kernel(
    const unsigned short* __restrict__ feat, const unsigned short* __restrict__ WxT,
    const float* __restrict__ bias4, unsigned short* __restrict__ pre)
{
  __shared__ __align__(16) unsigned short Abuf[128 * 64];
  __shared__ __align__(16) unsigned short Bbuf[128 * 64];
  int tid = threadIdx.x, w = tid >> 6, lane = tid & 63;
  int m0 = blockIdx.x * 128, n0 = blockIdx.y * 128;
  int wm = w >> 1, wn = w & 1;
  f32x4 acc[4][4];
  #pragma unroll
  for (int i = 0; i < 4; ++i)
    #pragma unroll
    for (int j = 0; j < 4; ++j) acc[i][j] = (f32x4){0.f, 0.f, 0.f, 0.f};

  #pragma unroll 1
  for (int ks = 0; ks < 4; ++ks) {
    int k0 = ks * 64;
    #pragma unroll
    for (int i = 0; i < 4; ++i) {
      int c = i * 256 + tid;
      int row = c >> 3, cc = c & 7;
      const unsigned short* ga = feat + (size_t)(m0 + row) * 256 + (k0 + cc * 8);
      const unsigned short* gb = WxT + (size_t)(n0 + row) * 256 + (k0 + cc * 8);
      char* la = (char*)Abuf + (size_t)(i * 256 + w * 64) * 16;
      char* lb = (char*)Bbuf + (size_t)(i * 256 + w * 64) * 16;
      GLD_LDS16(ga, la);
      GLD_LDS16(gb, lb);
    }
    __syncthreads();
    #pragma unroll
    for (int kk = 0; kk < 2; ++kk) {
      int k = kk * 32 + (lane >> 4) * 8;
      bf16x8 a[4], b[4];
      #pragma unroll
      for (int mt = 0; mt < 4; ++mt) {
        int row = wm * 64 + mt * 16 + (lane & 15);
        a[mt] = *reinterpret_cast<const bf16x8*>(&Abuf[row * 64 + k]);
      }
      #pragma unroll
      for (int nt = 0; nt < 4; ++nt) {
        int col = wn * 64 + nt * 16 + (lane & 15);
        b[nt] = *reinterpret_cast<const bf16x8*>(&Bbuf[col * 64 + k]);
      }
      #pragma unroll
      for (int mt = 0; mt < 4; ++mt)
        #pragma unroll
        for (int nt = 0; nt < 4; ++nt)
          acc[mt][nt] = __builtin_amdgcn_mfma_f32_16x16x32_bf16(a[mt], b[nt], acc[mt][nt], 0, 0, 0);
    }
    __syncthreads();
  }
  #pragma unroll
  for (int nt = 0; nt < 4; ++nt) {
    int col = n0 + wn * 64 + nt * 16 + (lane & 15);
    float bv = bias4[col];
    #pragma unroll
    for (int mt = 0; mt < 4; ++mt)
      #pragma unroll
      for (int r = 0; r < 4; ++r) {
        int row = m0 + wm * 64 + mt * 16 + (lane >> 4) * 4 + r;
        pre[(size_t)row * 1024 + col] = f2bf(acc[mt][nt][r] + bv);
      }
  }
}

// ---------------------------------------------------------------- k4: recurrent scan, 1 WG/batch
// thread (w=tid>>6, l=tid&63): j0 = w*32+(l&31) in [0,256), k-half hf = l>>5.
// Owns all 4 gate columns {g*256+j0}, k in [hf*128, hf*128+128).
// 128 weight dwords live in PHYSICAL AGPRs a0..a127 (gate g -> a[32g..32g+31]).
#define WRA(n, val) asm volatile("v_accvgpr_write_b32 a" #n ", %0" :: "v"(val) : "a" #n)
#define WR4(n0,n1,n2,n3, q) \
  do { WRA(n0,(q).x); WRA(n1,(q).y); WRA(n2,(q).z); WRA(n3,(q).w); } while (0)
#define RDA(n) __extension__({ int _r; \
  asm volatile("v_accvgpr_read_b32 %0, a" #n : "=v"(_r) :: "a" #n); _r; })
#define D4A(acc, H, n0,n1,n2,n3) do { \
  acc = dot4i8(RDA(n0), (H).x, acc); acc = dot4i8(RDA(n1), (H).y, acc); \
  acc = dot4i8(RDA(n2), (H).z, acc); acc = dot4i8(RDA(n3), (H).w, acc); } while (0)

__global__ __attribute__((amdgpu_flat_work_group_size(512, 512)))
           __attribute__((amdgpu_waves_per_eu(2, 2)))
void scan_kernel(
    const unsigned short* __restrict__ pre, const float* __restrict__ dt,
    const signed char* __restrict__ wq, const float* __restrict__ sw,
    int* __restrict__ hstate, unsigned short* __restrict__ hseq, int s0, int C)
{
  __shared__ int hq2[2][64];
  int tid = threadIdx.x, w = tid >> 6, l = tid & 63;
  int b = blockIdx.x;
  int j0 = w * 32 + (l & 31);
  int hf = l >> 5;

  // stage 128 weight dwords into physical AGPRs (8 int4 loads in flight per group)
  {
    const int4* wp = (const int4*)(wq + (size_t)tid * 512);
    int4 q0, q1, q2, q3, q4, q5, q6, q7;
    q0=wp[0]; q1=wp[1]; q2=wp[2]; q3=wp[3]; q4=wp[4]; q5=wp[5]; q6=wp[6]; q7=wp[7];
    WR4(0,1,2,3,q0);     WR4(4,5,6,7,q1);     WR4(8,9,10,11,q2);    WR4(12,13,14,15,q3);
    WR4(16,17,18,19,q4); WR4(20,21,22,23,q5); WR4(24,25,26,27,q6);  WR4(28,29,30,31,q7);
    q0=wp[8]; q1=wp[9]; q2=wp[10]; q3=wp[11]; q4=wp[12]; q5=wp[13]; q6=wp[14]; q7=wp[15];
    WR4(32,33,34,35,q0); WR4(36,37,38,39,q1); WR4(40,41,42,43,q2);  WR4(44,45,46,47,q3);
    WR4(48,49,50,51,q4); WR4(52,53,54,55,q5); WR4(56,57,58,59,q6);  WR4(60,61,62,63,q7);
    q0=wp[16]; q1=wp[17]; q2=wp[18]; q3=wp[19]; q4=wp[20]; q5=wp[21]; q6=wp[22]; q7=wp[23];
    WR4(64,65,66,67,q0); WR4(68,69,70,71,q1); WR4(72,73,74,75,q2);  WR4(76,77,78,79,q3);
    WR4(80,81,82,83,q4); WR4(84,85,86,87,q5); WR4(88,89,90,91,q6);  WR4(92,93,94,95,q7);
    q0=wp[24]; q1=wp[25]; q2=wp[26]; q3=wp[27]; q4=wp[28]; q5=wp[29]; q6=wp[30]; q7=wp[31];
    WR4(96,97,98,99,q0);   WR4(100,101,102,103,q1); WR4(104,105,106,107,q2); WR4(108,109,110,111,q3);
    WR4(112,113,114,115,q4); WR4(116,117,118,119,q5); WR4(120,121,122,123,q6); WR4(124,125,126,127,q7);
  }

  float sc0 = sw[j0]       * (1.f / 127.f);
  float sc1 = sw[256 + j0] * (1.f / 127.f);
  float sc2 = sw[512 + j0] * (1.f / 127.f);
  float sc3 = sw[768 + j0] * (1.f / 127.f);

  if (tid < 64) hq2[0][tid] = (s0 == 0) ? 0 : hstate[b * 64 + tid];

  const unsigned short* preB = pre + (size_t)b * C * 1024;
  unsigned short* hsB = hseq + (size_t)b * C * 256;
  // prefetch step 0
  unsigned short pu0 = preB[j0], pu1 = preB[256 + j0], pu2 = preB[512 + j0], pu3 = preB[768 + j0];
  float dtc = dt[b * SS + s0] * 10.f;
  int cur = 0;
  __syncthreads();

  for (int cs = 0; cs < C; ++cs) {
    // prefetch next step's pre/dt (independent of hq -> overlaps the dot)
    unsigned short qn0 = 0, qn1 = 0, qn2 = 0, qn3 = 0; float dtn = 0.f;
    if (cs + 1 < C) {
      const unsigned short* pn = preB + (size_t)(cs + 1) * 1024;
      qn0 = pn[j0]; qn1 = pn[256 + j0]; qn2 = pn[512 + j0]; qn3 = pn[768 + j0];
      dtn = dt[b * SS + s0 + cs + 1] * 10.f;
    }
    const int4* hv4 = (const int4*)hq2[cur] + hf * 8;   // broadcast reads (same addr per half)
    int4 h0 = hv4[0], h1 = hv4[1], h2 = hv4[2], h3 = hv4[3];
    int4 h4 = hv4[4], h5 = hv4[5], h6 = hv4[6], h7 = hv4[7];
    int a0 = 0, a1 = 0, a2 = 0, a3 = 0;
    // 4-way interleave across gate accumulators for ILP
    D4A(a0,h0,0,1,2,3);       D4A(a1,h0,32,33,34,35);   D4A(a2,h0,64,65,66,67);     D4A(a3,h0,96,97,98,99);
    D4A(a0,h1,4,5,6,7);       D4A(a1,h1,36,37,38,39);   D4A(a2,h1,68,69,70,71);     D4A(a3,h1,100,101,102,103);
    D4A(a0,h2,8,9,10,11);     D4A(a1,h2,40,41,42,43);   D4A(a2,h2,72,73,74,75);     D4A(a3,h2,104,105,106,107);
    D4A(a0,h3,12,13,14,15);   D4A(a1,h3,44,45,46,47);   D4A(a2,h3,76,77,78,79);     D4A(a3,h3,108,109,110,111);
    D4A(a0,h4,16,17,18,19);   D4A(a1,h4,48,49,50,51);   D4A(a2,h4,80,81,82,83);     D4A(a3,h4,112,113,114,115);
    D4A(a0,h5,20,21,22,23);   D4A(a1,h5,52,53,54,55);   D4A(a2,h5,84,85,86,87);     D4A(a3,h5,116,117,118,119);
    D4A(a0,h6,24,25,26,27);   D4A(a1,h6,56,57,58,59);   D4A(a2,h6,88,89,90,91);     D4A(a3,h6,120,121,122,123);
    D4A(a0,h7,28,29,30,31);   D4A(a1,h7,60,61,62,63);   D4A(a2,h7,92,93,94,95);     D4A(a3,h7,124,125,126,127);
    a0 += __shfl_xor(a0, 32, 64);
    a1 += __shfl_xor(a1, 32, 64);
    a2 += __shfl_xor(a2, 32, 64);
    a3 += __shfl_xor(a3, 32, 64);
    float g0 = (float)a0 * sc0 + bf2f(pu0);
    float g1 = (float)a1 * sc1 + bf2f(pu1);
    float g2 = (float)a2 * sc2 + bf2f(pu2);
    float g3 = (float)a3 * sc3 + bf2f(pu3);
    float f1 = tanh_f(g0), f2 = tanh_f(g1);
    float ti = sigm(g2 * dtc + g3);
    float h = f1 + ti * (f2 - f1);
    int q = (int)rintf(h * 127.f);
    q = q > 127 ? 127 : (q < -127 ? -127 : q);
    if (l < 32) {
      ((signed char*)hq2[cur ^ 1])[j0] = (signed char)q;
      hsB[(size_t)cs * 256 + j0] = f2bf(h);
    }
    pu0 = qn0; pu1 = qn1; pu2 = qn2; pu3 = qn3; dtc = dtn;
    cur ^= 1;
    __syncthreads();
  }
  if (tid < 64) hstate[b * 64 + tid] = hq2[cur][tid];
}

// ---------------------------------------------------------------- k5: head from hseq
__global__ __launch_bounds__(256) void head_kernel(
    const unsigned short* __restrict__ hseq, const float* __restrict__ gW,
    const float* __restrict__ scal, float* __restrict__ out, int s0, int C, int cshift)
{
  int tid = threadIdx.x, wv = tid >> 6, l = tid & 63;
  int row = blockIdx.x * 4 + wv;                 // row in [0, B*C)
  const unsigned short* hr = hseq + (size_t)row * 256 + l * 4;
  ushort4 u = *reinterpret_cast<const ushort4*>(hr);
  float4 gw = *reinterpret_cast<const float4*>(gW + l * 4);
  float v0 = bf2f(u.x), v1 = bf2f(u.y), v2 = bf2f(u.z), v3 = bf2f(u.w);
  float s1 = v0 + v1 + v2 + v3;
  float s2 = v0 * v0 + v1 * v1 + v2 * v2 + v3 * v3;
  float s3 = v0 * gw.x + v1 * gw.y + v2 * gw.z + v3 * gw.w;
  for (int m = 32; m >= 1; m >>= 1) {
    s1 += __shfl_xor(s1, m, 64); s2 += __shfl_xor(s2, m, 64); s3 += __shfl_xor(s3, m, 64);
  }
  if (l == 0) {
    float mean = s1 * (1.f / 256.f);
    float var = s2 * (1.f / 256.f) - mean * mean;
    float inv = rsqrtf(var + 1e-5f);
    int b = row >> cshift, cs = row & (C - 1);
    out[(size_t)b * SS + s0 + cs] = inv * (s3 - mean * scal[0]) + scal[1];
  }
}

// ---------------------------------------------------------------- launch
extern "C" void kernel_launch(void* const* d_in, const int* in_sizes, int n_in,
                              void* d_out, int out_size, void* d_ws, size_t ws_size,
                              hipStream_t stream)
{
  (void)in_sizes; (void)n_in; (void)out_size;
  const float* x        = (const float*)d_in[0];
  const float* dt       = (const float*)d_in[1];
  const float* ln_in_g  = (const float*)d_in[2];
  const float* ln_in_b  = (const float*)d_in[3];
  const float* proj_W   = (const float*)d_in[4];
  const float* proj_b   = (const float*)d_in[5];
  const float* ln_p_g   = (const float*)d_in[6];
  const float* ln_p_b   = (const float*)d_in[7];
  const float* W_ff1    = (const float*)d_in[8];
  const float* b_ff1    = (const float*)d_in[9];
  const float* W_ff2    = (const float*)d_in[10];
  const float* b_ff2    = (const float*)d_in[11];
  const float* W_ta     = (const float*)d_in[12];
  const float* b_ta     = (const float*)d_in[13];
  const float* W_tb     = (const float*)d_in[14];
  const float* b_tb     = (const float*)d_in[15];
  const float* head_g   = (const float*)d_in[16];
  const float* head_b   = (const float*)d_in[17];
  const float* head_W   = (const float*)d_in[18];
  const float* head_bias= (const float*)d_in[19];

  char* ws = (char*)d_ws;
  unsigned short* WxT = (unsigned short*)(ws + OFF_WXT);
  signed char* wq     = (signed char*)(ws + OFF_WQ);
  float* sw           = (float*)(ws + OFF_SW);
  float* bias4        = (float*)(ws + OFF_BIAS4);
  unsigned short* PWT = (unsigned short*)(ws + OFF_PWT);
  float* gWv          = (float*)(ws + OFF_GW);
  float* scal         = (float*)(ws + OFF_SCAL);
  int* hstate         = (int*)(ws + OFF_HST);

  int C = 16;
  for (int c = 2048; c >= 16; c >>= 1) {
    size_t need = OFF_FEAT + (size_t)c * 65536 + (size_t)c * 262144;
    if (need <= ws_size) { C = c; break; }
  }
  unsigned short* featb = (unsigned short*)(ws + OFF_FEAT);   // feat, then hseq
  unsigned short* preb  = (unsigned short*)(ws + OFF_FEAT + (size_t)C * 65536);
  int cshift = 31 - __builtin_clz((unsigned)C);

  prep_kernel<<<2049, 256, 0, stream>>>(proj_W, W_ff1, b_ff1, W_ff2, b_ff2, W_ta, b_ta, W_tb, b_tb,
                                        head_g, head_b, head_W, head_bias,
                                        WxT, wq, sw, bias4, PWT, gWv, scal);
  int nch = SS / C;
  for (int ch = 0; ch < nch; ++ch) {
    int s0 = ch * C;
    feat_kernel<<<dim3(BB * C / 64), 512, 0, stream>>>(x, ln_in_g, ln_in_b, proj_b, ln_p_g, ln_p_b,
                                                       PWT, featb, s0, C, cshift);
    gemm_kernel<<<dim3(BB * C / 128, 8), 256, 0, stream>>>(featb, WxT, bias4, preb);
    scan_kernel<<<dim3(BB), 512, 0, stream>>>(preb, dt, wq, sw, hstate, featb, s0, C);
    head_kernel<<<dim3(BB * C / 4), 256, 0, stream>>>(featb, gWv, scal, (float*)d_out, s0, C, cshift);
  }
}

// Round 8
// 3752.158 us; speedup vs baseline: 1.0560x; 1.0560x over previous
//
#include <hip/hip_runtime.h>

// StructLNN: LN(67) -> Linear(67,256)+LN+SiLU -> CfC scan (2048 steps) -> LN head -> [B,S,1]
//   prep: repack weights (W_x^T bf16 for GEMM, W_h int8 per-column quant in scan-thread layout)
//   k2 feat_kernel: input LN + MFMA proj + LN + SiLU -> feat bf16
//   k3 gemm_kernel: pre = feat @ W_x^T + bias4 (bf16 MFMA)
//   k4 scan_kernel: 1 WG/batch, 512 thr; thread owns h-index j0 for all 4 gates, k-half hf.
//      Weights in PHYSICAL AGPRs a0..a127. r7: VOP3P dot REJECTS AGPR src -> must
//      v_accvgpr_read. r6 (1 read per volatile block) serialized at 4290 cyc/step.
//      Now: 4 reads per volatile block + C-level builtin sdot4 (schedulable) -> compiler
//      interleaves dots with subsequent read blocks. Floor 1024 cyc/step issue.
//      r2-r5: compiler-managed storage always spills/streams (~625us L2-bound floor).
//   k5 head_kernel: folded LN+head over hseq (memory-bound).

typedef __bf16 bf16x8 __attribute__((ext_vector_type(8)));
typedef float f32x4 __attribute__((ext_vector_type(4)));

#define DEVFN static __device__ __forceinline__

DEVFN float bf2f(unsigned short u){ return __uint_as_float(((unsigned)u) << 16); }
DEVFN unsigned short f2bf(float f){
  unsigned x = __float_as_uint(f);
  return (unsigned short)((x + 0x7FFFu + ((x >> 16) & 1u)) >> 16);
}
DEVFN float sigm(float x){ return 1.f / (1.f + __expf(-x)); }
DEVFN float tanh_f(float x){ return 1.f - 2.f / (__expf(2.f * x) + 1.f); }

#if __has_builtin(__builtin_amdgcn_sdot4)
DEVFN int dot4i8(int a, int b, int c){ return __builtin_amdgcn_sdot4(a, b, c, false); }
#else
DEVFN int dot4i8(int a, int b, int c){
  c += (int)(signed char)(a & 0xff)        * (int)(signed char)(b & 0xff);
  c += (int)(signed char)((a >> 8) & 0xff) * (int)(signed char)((b >> 8) & 0xff);
  c += (int)(signed char)((a >> 16) & 0xff)* (int)(signed char)((b >> 16) & 0xff);
  c += (a >> 24) * (b >> 24);
  return c;
}
#endif

#define GLD_LDS16(g, l) \
  __builtin_amdgcn_global_load_lds((const __attribute__((address_space(1))) void*)(g), \
                                   (__attribute__((address_space(3))) void*)(l), 16, 0, 0)

static constexpr int BB = 128;
static constexpr int SS = 2048;
static constexpr int DD = 67;

// ws layout (bytes)
static constexpr size_t OFF_WXT   = 0;         // bf16 [1024][256]  W_x^T (x-part of 4 mats)
static constexpr size_t OFF_WQ    = 524288;    // i8   [512 thr][4 gates][128]  W_h^T quant, scan layout
static constexpr size_t OFF_SW    = 786432;    // f32  [1024] per-column scales
static constexpr size_t OFF_BIAS4 = 790528;    // f32  [1024] concat(b_ff1,b_ff2,b_ta,b_tb)
static constexpr size_t OFF_PWT   = 794624;    // bf16 [256][96] proj_W^T zero-padded
static constexpr size_t OFF_GW    = 843776;    // f32  [256] head_g*head_W
static constexpr size_t OFF_SCAL  = 844800;    // f32  [2]: S_gW, S_bW+head_bias
static constexpr size_t OFF_HST   = 845824;    // i32  [128][64] persisted packed-int8 h
static constexpr size_t OFF_FEAT  = 878592;    // bf16 [B*C][256] (feat, then reused as hseq)

// ---------------------------------------------------------------- prep
__global__ __launch_bounds__(256) void prep_kernel(
    const float* __restrict__ proj_W,
    const float* __restrict__ W_ff1, const float* __restrict__ b_ff1,
    const float* __restrict__ W_ff2, const float* __restrict__ b_ff2,
    const float* __restrict__ W_ta,  const float* __restrict__ b_ta,
    const float* __restrict__ W_tb,  const float* __restrict__ b_tb,
    const float* __restrict__ head_g, const float* __restrict__ head_b,
    const float* __restrict__ head_W, const float* __restrict__ head_bias,
    unsigned short* __restrict__ WxT, signed char* __restrict__ wq,
    float* __restrict__ sw, float* __restrict__ bias4,
    unsigned short* __restrict__ PWT, float* __restrict__ gW, float* __restrict__ scal)
{
  __shared__ float red[8];
  int bid = blockIdx.x, t = threadIdx.x;
  int wv = t >> 6, ln = t & 63;
  if (bid < 1024) {
    int J = bid, col = J & 255, which = J >> 8;
    const float* Wsrc = which == 0 ? W_ff1 : which == 1 ? W_ff2 : which == 2 ? W_ta : W_tb;
    const float* bsrc = which == 0 ? b_ff1 : which == 1 ? b_ff2 : which == 2 ? b_ta : b_tb;
    float w = Wsrc[t * 256 + col];          // x-part rows 0..255
    WxT[J * 256 + t] = f2bf(w);
    if (t == 0) bias4[J] = bsrc[col];
  } else if (bid < 2048) {
    int J = bid - 1024, col = J & 255, which = J >> 8;
    const float* Wsrc = which == 0 ? W_ff1 : which == 1 ? W_ff2 : which == 2 ? W_ta : W_tb;
    float w = Wsrc[(256 + t) * 256 + col];  // h-part rows 256..511, k = t
    float a = fabsf(w);
    for (int m = 32; m >= 1; m >>= 1) a = fmaxf(a, __shfl_xor(a, m, 64));
    if (ln == 0) red[wv] = a;
    __syncthreads();
    a = fmaxf(fmaxf(red[0], red[1]), fmaxf(red[2], red[3]));
    float scale = (a > 0.f) ? a * (1.f / 127.f) : 1.f;
    int q = (int)rintf(w / scale);
    q = q > 127 ? 127 : (q < -127 ? -127 : q);
    // scan-thread layout: thread st owns (j0=col, k-half hf=t>>7), gate=which, ki=t&127
    int st = (col >> 5) * 64 + (t >> 7) * 32 + (col & 31);
    wq[(size_t)st * 512 + which * 128 + (t & 127)] = (signed char)q;
    if (t == 0) sw[J] = scale;
  } else {
    for (int idx = t; idx < 256 * 96; idx += 256) {
      int j = idx / 96, d = idx % 96;
      float v = (d < DD) ? proj_W[d * 256 + j] : 0.f;
      PWT[idx] = f2bf(v);
    }
    float gw = head_g[t] * head_W[t];
    gW[t] = gw;
    float bw = head_b[t] * head_W[t];
    float s1 = gw, s2 = bw;
    for (int m = 32; m >= 1; m >>= 1) { s1 += __shfl_xor(s1, m, 64); s2 += __shfl_xor(s2, m, 64); }
    if (ln == 0) { red[wv] = s1; red[4 + wv] = s2; }
    __syncthreads();
    if (t == 0) {
      scal[0] = red[0] + red[1] + red[2] + red[3];
      scal[1] = red[4] + red[5] + red[6] + red[7] + head_bias[0];
    }
  }
}

// ---------------------------------------------------------------- k2: x -> feat
__global__ __launch_bounds__(512) void feat_kernel(
    const float* __restrict__ x, const float* __restrict__ ln_in_g, const float* __restrict__ ln_in_b,
    const float* __restrict__ proj_b, const float* __restrict__ ln_p_g, const float* __restrict__ ln_p_b,
    const unsigned short* __restrict__ PWT, unsigned short* __restrict__ feat,
    int s0, int C, int cshift)
{
  __shared__ __align__(16) unsigned short XA[64 * 104];
  __shared__ __align__(16) unsigned short XB[256 * 96];
  __shared__ float partS[64][4], partQ[64][4], statM[64], statI[64];
  int tid = threadIdx.x, w = tid >> 6, lane = tid & 63;
  int r0 = blockIdx.x * 64;

  {
    float g1v = (lane < 67) ? ln_in_g[lane] : 0.f;
    float b1v = (lane < 67) ? ln_in_b[lane] : 0.f;
    float g2v = (lane < 3) ? ln_in_g[64 + lane] : 0.f;
    float b2v = (lane < 3) ? ln_in_b[64 + lane] : 0.f;
    for (int i = 0; i < 8; ++i) {
      int rl = w * 8 + i;
      int r = r0 + rl;
      int bb = r >> cshift, cs = r & (C - 1);
      const float* xr = x + (size_t)(bb * SS + s0 + cs) * DD;
      float v0 = (lane < 67) ? xr[lane] : 0.f;
      float v1 = (lane < 3) ? xr[64 + lane] : 0.f;
      float s = v0 + v1, q = v0 * v0 + v1 * v1;
      for (int m = 32; m >= 1; m >>= 1) { s += __shfl_xor(s, m, 64); q += __shfl_xor(q, m, 64); }
      float mean = s * (1.f / 67.f);
      float var = q * (1.f / 67.f) - mean * mean;
      float inv = rsqrtf(var + 1e-5f);
      float xn0 = (v0 - mean) * inv * g1v + b1v;
      float xn1 = (v1 - mean) * inv * g2v + b2v;
      XA[rl * 104 + lane] = (lane < 67) ? f2bf(xn0) : (unsigned short)0;
      if (lane < 40) XA[rl * 104 + 64 + lane] = (lane < 3) ? f2bf(xn1) : (unsigned short)0;
    }
  }
  {
    const unsigned int* src = (const unsigned int*)PWT;
    unsigned int* dst = (unsigned int*)XB;
    for (int idx = tid; idx < 256 * 48; idx += 512) dst[idx] = src[idx];
  }
  __syncthreads();

  int wm = w >> 2, wn = w & 3;
  f32x4 acc[2][4];
  #pragma unroll
  for (int mt = 0; mt < 2; ++mt)
    #pragma unroll
    for (int nt = 0; nt < 4; ++nt) acc[mt][nt] = (f32x4){0.f, 0.f, 0.f, 0.f};
  #pragma unroll
  for (int ks = 0; ks < 3; ++ks) {
    int k = ks * 32 + (lane >> 4) * 8;
    bf16x8 a[2], b[4];
    #pragma unroll
    for (int mt = 0; mt < 2; ++mt) {
      int row = wm * 32 + mt * 16 + (lane & 15);
      a[mt] = *reinterpret_cast<const bf16x8*>(&XA[row * 104 + k]);
    }
    #pragma unroll
    for (int nt = 0; nt < 4; ++nt) {
      int col = wn * 64 + nt * 16 + (lane & 15);
      b[nt] = *reinterpret_cast<const bf16x8*>(&XB[col * 96 + k]);
    }
    #pragma unroll
    for (int mt = 0; mt < 2; ++mt)
      #pragma unroll
      for (int nt = 0; nt < 4; ++nt)
        acc[mt][nt] = __builtin_amdgcn_mfma_f32_16x16x32_bf16(a[mt], b[nt], acc[mt][nt], 0, 0, 0);
  }
  #pragma unroll
  for (int nt = 0; nt < 4; ++nt) {
    int col = wn * 64 + nt * 16 + (lane & 15);
    float pb = proj_b[col];
    #pragma unroll
    for (int mt = 0; mt < 2; ++mt)
      #pragma unroll
      for (int r = 0; r < 4; ++r) acc[mt][nt][r] += pb;
  }
  #pragma unroll
  for (int mt = 0; mt < 2; ++mt) {
    #pragma unroll
    for (int r = 0; r < 4; ++r) {
      float s = 0.f, q = 0.f;
      #pragma unroll
      for (int nt = 0; nt < 4; ++nt) { float v = acc[mt][nt][r]; s += v; q += v * v; }
      for (int m = 1; m < 16; m <<= 1) { s += __shfl_xor(s, m, 16); q += __shfl_xor(q, m, 16); }
      if ((lane & 15) == 0) {
        int row = wm * 32 + mt * 16 + (lane >> 4) * 4 + r;
        partS[row][wn] = s; partQ[row][wn] = q;
      }
    }
  }
  __syncthreads();
  if (tid < 64) {
    float s = partS[tid][0] + partS[tid][1] + partS[tid][2] + partS[tid][3];
    float q = partQ[tid][0] + partQ[tid][1] + partQ[tid][2] + partQ[tid][3];
    float mean = s * (1.f / 256.f);
    float var = q * (1.f / 256.f) - mean * mean;
    statM[tid] = mean; statI[tid] = rsqrtf(var + 1e-5f);
  }
  __syncthreads();
  #pragma unroll
  for (int nt = 0; nt < 4; ++nt) {
    int col = wn * 64 + nt * 16 + (lane & 15);
    float gc = ln_p_g[col], bc = ln_p_b[col];
    #pragma unroll
    for (int mt = 0; mt < 2; ++mt)
      #pragma unroll
      for (int r = 0; r < 4; ++r) {
        int row = wm * 32 + mt * 16 + (lane >> 4) * 4 + r;
        float v = acc[mt][nt][r];
        float y = (v - statM[row]) * statI[row] * gc + bc;
        float sl = y * sigm(y);
        feat[(size_t)(r0 + row) * 256 + col] = f2bf(sl);
      }
  }
}

// ---------------------------------------------------------------- k3: pre = feat @ WxT + bias4
__global__ __launch_bounds__(256, 2) void gemm_kernel(
    const unsigned short* __restrict__ feat, const unsigned short* __restrict__ WxT,
    const float* __restrict__ bias4, unsigned short* __restrict__ pre)
{
  __shared__ __align__(16) unsigned short Abuf[128 * 64];
  __shared__ __align__(16) unsigned short Bbuf[128 * 64];
  int tid = threadIdx.x, w = tid >> 6, lane = tid & 63;
  int m0 = blockIdx.x * 128, n0 = blockIdx.y * 128;
  int wm = w >> 1, wn = w & 1;
  f32x4 acc[4][4];
  #pragma unroll
  for (int i = 0; i < 4; ++i)
    #pragma unroll
    for (int j = 0; j < 4; ++j) acc[i][j] = (f32x4){0.f, 0.f, 0.f, 0.f};

  #pragma unroll 1
  for (int ks = 0; ks < 4; ++ks) {
    int k0 = ks * 64;
    #pragma unroll
    for (int i = 0; i < 4; ++i) {
      int c = i * 256 + tid;
      int row = c >> 3, cc = c & 7;
      const unsigned short* ga = feat + (size_t)(m0 + row) * 256 + (k0 + cc * 8);
      const unsigned short* gb = WxT + (size_t)(n0 + row) * 256 + (k0 + cc * 8);
      char* la = (char*)Abuf + (size_t)(i * 256 + w * 64) * 16;
      char* lb = (char*)Bbuf + (size_t)(i * 256 + w * 64) * 16;
      GLD_LDS16(ga, la);
      GLD_LDS16(gb, lb);
    }
    __syncthreads();
    #pragma unroll
    for (int kk = 0; kk < 2; ++kk) {
      int k = kk * 32 + (lane >> 4) * 8;
      bf16x8 a[4], b[4];
      #pragma unroll
      for (int mt = 0; mt < 4; ++mt) {
        int row = wm * 64 + mt * 16 + (lane & 15);
        a[mt] = *reinterpret_cast<const bf16x8*>(&Abuf[row * 64 + k]);
      }
      #pragma unroll
      for (int nt = 0; nt < 4; ++nt) {
        int col = wn * 64 + nt * 16 + (lane & 15);
        b[nt] = *reinterpret_cast<const bf16x8*>(&Bbuf[col * 64 + k]);
      }
      #pragma unroll
      for (int mt = 0; mt < 4; ++mt)
        #pragma unroll
        for (int nt = 0; nt < 4; ++nt)
          acc[mt][nt] = __builtin_amdgcn_mfma_f32_16x16x32_bf16(a[mt], b[nt], acc[mt][nt], 0, 0, 0);
    }
    __syncthreads();
  }
  #pragma unroll
  for (int nt = 0; nt < 4; ++nt) {
    int col = n0 + wn * 64 + nt * 16 + (lane & 15);
    float bv = bias4[col];
    #pragma unroll
    for (int mt = 0; mt < 4; ++mt)
      #pragma unroll
      for (int r = 0; r < 4; ++r) {
        int row = m0 + wm * 64 + mt * 16 + (lane >> 4) * 4 + r;
        pre[(size_t)row * 1024 + col] = f2bf(acc[mt][nt][r] + bv);
      }
  }
}

// ---------------------------------------------------------------- k4: recurrent scan, 1 WG/batch
// thread (w=tid>>6, l=tid&63): j0 = w*32+(l&31) in [0,256), k-half hf = l>>5.
// Owns all 4 gate columns {g*256+j0}, k in [hf*128, hf*128+128).
// 128 weight dwords in PHYSICAL AGPRs: gate g, h-dword idx -> a[32g + idx].
// In-loop: batched volatile reads (4/block, one per gate) + schedulable builtin dots.
#define WRA(n, val) asm volatile("v_accvgpr_write_b32 a" #n ", %0" :: "v"(val) : "a" #n)
#define WR4(n0,n1,n2,n3, q) \
  do { WRA(n0,(q).x); WRA(n1,(q).y); WRA(n2,(q).z); WRA(n3,(q).w); } while (0)
#define RD4(o0,o1,o2,o3, n0,n1,n2,n3) \
  asm volatile("v_accvgpr_read_b32 %0, a" #n0 "\n\t" \
               "v_accvgpr_read_b32 %1, a" #n1 "\n\t" \
               "v_accvgpr_read_b32 %2, a" #n2 "\n\t" \
               "v_accvgpr_read_b32 %3, a" #n3 \
               : "=v"(o0), "=v"(o1), "=v"(o2), "=v"(o3))
#define DOTB(hx, n0,n1,n2,n3) do { int _w0,_w1,_w2,_w3; \
  RD4(_w0,_w1,_w2,_w3, n0,n1,n2,n3); \
  d0 = dot4i8(_w0,(hx),d0); d1 = dot4i8(_w1,(hx),d1); \
  d2 = dot4i8(_w2,(hx),d2); d3 = dot4i8(_w3,(hx),d3); } while (0)

__global__ __attribute__((amdgpu_flat_work_group_size(512, 512)))
           __attribute__((amdgpu_waves_per_eu(2, 2)))
void scan_kernel(
    const unsigned short* __restrict__ pre, const float* __restrict__ dt,
    const signed char* __restrict__ wq, const float* __restrict__ sw,
    int* __restrict__ hstate, unsigned short* __restrict__ hseq, int s0, int C)
{
  __shared__ int hq2[2][64];
  int tid = threadIdx.x, w = tid >> 6, l = tid & 63;
  int b = blockIdx.x;
  int j0 = w * 32 + (l & 31);
  int hf = l >> 5;

  // stage 128 weight dwords into physical AGPRs
  {
    const int4* wp = (const int4*)(wq + (size_t)tid * 512);
    int4 q0, q1, q2, q3, q4, q5, q6, q7;
    q0=wp[0]; q1=wp[1]; q2=wp[2]; q3=wp[3]; q4=wp[4]; q5=wp[5]; q6=wp[6]; q7=wp[7];
    WR4(0,1,2,3,q0);     WR4(4,5,6,7,q1);     WR4(8,9,10,11,q2);    WR4(12,13,14,15,q3);
    WR4(16,17,18,19,q4); WR4(20,21,22,23,q5); WR4(24,25,26,27,q6);  WR4(28,29,30,31,q7);
    q0=wp[8]; q1=wp[9]; q2=wp[10]; q3=wp[11]; q4=wp[12]; q5=wp[13]; q6=wp[14]; q7=wp[15];
    WR4(32,33,34,35,q0); WR4(36,37,38,39,q1); WR4(40,41,42,43,q2);  WR4(44,45,46,47,q3);
    WR4(48,49,50,51,q4); WR4(52,53,54,55,q5); WR4(56,57,58,59,q6);  WR4(60,61,62,63,q7);
    q0=wp[16]; q1=wp[17]; q2=wp[18]; q3=wp[19]; q4=wp[20]; q5=wp[21]; q6=wp[22]; q7=wp[23];
    WR4(64,65,66,67,q0); WR4(68,69,70,71,q1); WR4(72,73,74,75,q2);  WR4(76,77,78,79,q3);
    WR4(80,81,82,83,q4); WR4(84,85,86,87,q5); WR4(88,89,90,91,q6);  WR4(92,93,94,95,q7);
    q0=wp[24]; q1=wp[25]; q2=wp[26]; q3=wp[27]; q4=wp[28]; q5=wp[29]; q6=wp[30]; q7=wp[31];
    WR4(96,97,98,99,q0);   WR4(100,101,102,103,q1); WR4(104,105,106,107,q2); WR4(108,109,110,111,q3);
    WR4(112,113,114,115,q4); WR4(116,117,118,119,q5); WR4(120,121,122,123,q6); WR4(124,125,126,127,q7);
  }

  float sc0 = sw[j0]       * (1.f / 127.f);
  float sc1 = sw[256 + j0] * (1.f / 127.f);
  float sc2 = sw[512 + j0] * (1.f / 127.f);
  float sc3 = sw[768 + j0] * (1.f / 127.f);

  if (tid < 64) hq2[0][tid] = (s0 == 0) ? 0 : hstate[b * 64 + tid];

  const unsigned short* preB = pre + (size_t)b * C * 1024;
  unsigned short* hsB = hseq + (size_t)b * C * 256;
  // prefetch step 0
  unsigned short pu0 = preB[j0], pu1 = preB[256 + j0], pu2 = preB[512 + j0], pu3 = preB[768 + j0];
  float dtc = dt[b * SS + s0] * 10.f;
  int cur = 0;
  __syncthreads();

  for (int cs = 0; cs < C; ++cs) {
    // prefetch next step's pre/dt (independent of hq -> overlaps the dot)
    unsigned short qn0 = 0, qn1 = 0, qn2 = 0, qn3 = 0; float dtn = 0.f;
    if (cs + 1 < C) {
      const unsigned short* pn = preB + (size_t)(cs + 1) * 1024;
      qn0 = pn[j0]; qn1 = pn[256 + j0]; qn2 = pn[512 + j0]; qn3 = pn[768 + j0];
      dtn = dt[b * SS + s0 + cs + 1] * 10.f;
    }
    const int4* hv4 = (const int4*)hq2[cur] + hf * 8;   // broadcast reads (same addr per half)
    int4 h0 = hv4[0], h1 = hv4[1], h2 = hv4[2], h3 = hv4[3];
    int4 h4 = hv4[4], h5 = hv4[5], h6 = hv4[6], h7 = hv4[7];
    int d0 = 0, d1 = 0, d2 = 0, d3 = 0;
    DOTB(h0.x,  0, 32, 64, 96);  DOTB(h0.y,  1, 33, 65, 97);
    DOTB(h0.z,  2, 34, 66, 98);  DOTB(h0.w,  3, 35, 67, 99);
    DOTB(h1.x,  4, 36, 68,100);  DOTB(h1.y,  5, 37, 69,101);
    DOTB(h1.z,  6, 38, 70,102);  DOTB(h1.w,  7, 39, 71,103);
    DOTB(h2.x,  8, 40, 72,104);  DOTB(h2.y,  9, 41, 73,105);
    DOTB(h2.z, 10, 42, 74,106);  DOTB(h2.w, 11, 43, 75,107);
    DOTB(h3.x, 12, 44, 76,108);  DOTB(h3.y, 13, 45, 77,109);
    DOTB(h3.z, 14, 46, 78,110);  DOTB(h3.w, 15, 47, 79,111);
    DOTB(h4.x, 16, 48, 80,112);  DOTB(h4.y, 17, 49, 81,113);
    DOTB(h4.z, 18, 50, 82,114);  DOTB(h4.w, 19, 51, 83,115);
    DOTB(h5.x, 20, 52, 84,116);  DOTB(h5.y, 21, 53, 85,117);
    DOTB(h5.z, 22, 54, 86,118);  DOTB(h5.w, 23, 55, 87,119);
    DOTB(h6.x, 24, 56, 88,120);  DOTB(h6.y, 25, 57, 89,121);
    DOTB(h6.z, 26, 58, 90,122);  DOTB(h6.w, 27, 59, 91,123);
    DOTB(h7.x, 28, 60, 92,124);  DOTB(h7.y, 29, 61, 93,125);
    DOTB(h7.z, 30, 62, 94,126);  DOTB(h7.w, 31, 63, 95,127);
    d0 += __shfl_xor(d0, 32, 64);
    d1 += __shfl_xor(d1, 32, 64);
    d2 += __shfl_xor(d2, 32, 64);
    d3 += __shfl_xor(d3, 32, 64);
    float g0 = (float)d0 * sc0 + bf2f(pu0);
    float g1 = (float)d1 * sc1 + bf2f(pu1);
    float g2 = (float)d2 * sc2 + bf2f(pu2);
    float g3 = (float)d3 * sc3 + bf2f(pu3);
    float f1 = tanh_f(g0), f2 = tanh_f(g1);
    float ti = sigm(g2 * dtc + g3);
    float h = f1 + ti * (f2 - f1);
    int q = (int)rintf(h * 127.f);
    q = q > 127 ? 127 : (q < -127 ? -127 : q);
    if (l < 32) {
      ((signed char*)hq2[cur ^ 1])[j0] = (signed char)q;
      hsB[(size_t)cs * 256 + j0] = f2bf(h);
    }
    pu0 = qn0; pu1 = qn1; pu2 = qn2; pu3 = qn3; dtc = dtn;
    cur ^= 1;
    __syncthreads();
  }
  if (tid < 64) hstate[b * 64 + tid] = hq2[cur][tid];
}

// ---------------------------------------------------------------- k5: head from hseq
__global__ __launch_bounds__(256) void head_kernel(
    const unsigned short* __restrict__ hseq, const float* __restrict__ gW,
    const float* __restrict__ scal, float* __restrict__ out, int s0, int C, int cshift)
{
  int tid = threadIdx.x, wv = tid >> 6, l = tid & 63;
  int row = blockIdx.x * 4 + wv;                 // row in [0, B*C)
  const unsigned short* hr = hseq + (size_t)row * 256 + l * 4;
  ushort4 u = *reinterpret_cast<const ushort4*>(hr);
  float4 gw = *reinterpret_cast<const float4*>(gW + l * 4);
  float v0 = bf2f(u.x), v1 = bf2f(u.y), v2 = bf2f(u.z), v3 = bf2f(u.w);
  float s1 = v0 + v1 + v2 + v3;
  float s2 = v0 * v0 + v1 * v1 + v2 * v2 + v3 * v3;
  float s3 = v0 * gw.x + v1 * gw.y + v2 * gw.z + v3 * gw.w;
  for (int m = 32; m >= 1; m >>= 1) {
    s1 += __shfl_xor(s1, m, 64); s2 += __shfl_xor(s2, m, 64); s3 += __shfl_xor(s3, m, 64);
  }
  if (l == 0) {
    float mean = s1 * (1.f / 256.f);
    float var = s2 * (1.f / 256.f) - mean * mean;
    float inv = rsqrtf(var + 1e-5f);
    int b = row >> cshift, cs = row & (C - 1);
    out[(size_t)b * SS + s0 + cs] = inv * (s3 - mean * scal[0]) + scal[1];
  }
}

// ---------------------------------------------------------------- launch
extern "C" void kernel_launch(void* const* d_in, const int* in_sizes, int n_in,
                              void* d_out, int out_size, void* d_ws, size_t ws_size,
                              hipStream_t stream)
{
  (void)in_sizes; (void)n_in; (void)out_size;
  const float* x        = (const float*)d_in[0];
  const float* dt       = (const float*)d_in[1];
  const float* ln_in_g  = (const float*)d_in[2];
  const float* ln_in_b  = (const float*)d_in[3];
  const float* proj_W   = (const float*)d_in[4];
  const float* proj_b   = (const float*)d_in[5];
  const float* ln_p_g   = (const float*)d_in[6];
  const float* ln_p_b   = (const float*)d_in[7];
  const float* W_ff1    = (const float*)d_in[8];
  const float* b_ff1    = (const float*)d_in[9];
  const float* W_ff2    = (const float*)d_in[10];
  const float* b_ff2    = (const float*)d_in[11];
  const float* W_ta     = (const float*)d_in[12];
  const float* b_ta     = (const float*)d_in[13];
  const float* W_tb     = (const float*)d_in[14];
  const float* b_tb     = (const float*)d_in[15];
  const float* head_g   = (const float*)d_in[16];
  const float* head_b   = (const float*)d_in[17];
  const float* head_W   = (const float*)d_in[18];
  const float* head_bias= (const float*)d_in[19];

  char* ws = (char*)d_ws;
  unsigned short* WxT = (unsigned short*)(ws + OFF_WXT);
  signed char* wq     = (signed char*)(ws + OFF_WQ);
  float* sw           = (float*)(ws + OFF_SW);
  float* bias4        = (float*)(ws + OFF_BIAS4);
  unsigned short* PWT = (unsigned short*)(ws + OFF_PWT);
  float* gWv          = (float*)(ws + OFF_GW);
  float* scal         = (float*)(ws + OFF_SCAL);
  int* hstate         = (int*)(ws + OFF_HST);

  int C = 16;
  for (int c = 2048; c >= 16; c >>= 1) {
    size_t need = OFF_FEAT + (size_t)c * 65536 + (size_t)c * 262144;
    if (need <= ws_size) { C = c; break; }
  }
  unsigned short* featb = (unsigned short*)(ws + OFF_FEAT);   // feat, then hseq
  unsigned short* preb  = (unsigned short*)(ws + OFF_FEAT + (size_t)C * 65536);
  int cshift = 31 - __builtin_clz((unsigned)C);

  prep_kernel<<<2049, 256, 0, stream>>>(proj_W, W_ff1, b_ff1, W_ff2, b_ff2, W_ta, b_ta, W_tb, b_tb,
                                        head_g, head_b, head_W, head_bias,
                                        WxT, wq, sw, bias4, PWT, gWv, scal);
  int nch = SS / C;
  for (int ch = 0; ch < nch; ++ch) {
    int s0 = ch * C;
    feat_kernel<<<dim3(BB * C / 64), 512, 0, stream>>>(x, ln_in_g, ln_in_b, proj_b, ln_p_g, ln_p_b,
                                                       PWT, featb, s0, C, cshift);
    gemm_kernel<<<dim3(BB * C / 128, 8), 256, 0, stream>>>(featb, WxT, bias4, preb);
    scan_kernel<<<dim3(BB), 512, 0, stream>>>(preb, dt, wq, sw, hstate, featb, s0, C);
    head_kernel<<<dim3(BB * C / 4), 256, 0, stream>>>(featb, gWv, scal, (float*)d_out, s0, C, cshift);
  }
}

// Round 9
// 2722.733 us; speedup vs baseline: 1.4553x; 1.3781x over previous
//
#include <hip/hip_runtime.h>

// StructLNN: LN(67) -> Linear(67,256)+LN+SiLU -> CfC scan (2048 steps) -> LN head -> [B,S,1]
//   prep: repack weights (W_x^T bf16 for GEMM; W_h int8 quantized, repacked as per-wave
//         MFMA B-fragments for the scan)
//   k2 feat_kernel: input LN + MFMA proj + LN + SiLU -> feat bf16
//   k3 gemm_kernel: pre = feat @ W_x^T + bias4 (bf16 MFMA)
//   k4 scan_kernel: 1 WG/batch, 8 waves. Weights in PHYSICAL AGPRs a0..a127; per step the
//      [1,256]@[256,1024] matvec runs as 32 v_mfma_i32_16x16x64_i8 per wave with B=a[N:N+3]
//      (MFMA reads AGPRs directly; VOP3P dots cannot - r7). A = h broadcast from LDS; all
//      16 D-rows equal -> row 0 free. Integer-exact == sdot version (r8 absmax 0.015625).
//      History: r2-r5 compiler-managed weights spill/stream (~625us L2-bound);
//      r6/r8 accvgpr_read+sdot VALU-issue-bound (~858us, active-CU VALUBusy ~71%).
//   k5 head_kernel: folded LN+head over hseq (memory-bound).

typedef __bf16 bf16x8 __attribute__((ext_vector_type(8)));
typedef float f32x4 __attribute__((ext_vector_type(4)));
typedef int i32x4 __attribute__((ext_vector_type(4)));

#define DEVFN static __device__ __forceinline__

DEVFN float bf2f(unsigned short u){ return __uint_as_float(((unsigned)u) << 16); }
DEVFN unsigned short f2bf(float f){
  unsigned x = __float_as_uint(f);
  return (unsigned short)((x + 0x7FFFu + ((x >> 16) & 1u)) >> 16);
}
DEVFN float sigm(float x){ return 1.f / (1.f + __expf(-x)); }
DEVFN float tanh_f(float x){ return 1.f - 2.f / (__expf(2.f * x) + 1.f); }

#define GLD_LDS16(g, l) \
  __builtin_amdgcn_global_load_lds((const __attribute__((address_space(1))) void*)(g), \
                                   (__attribute__((address_space(3))) void*)(l), 16, 0, 0)

static constexpr int BB = 128;
static constexpr int SS = 2048;
static constexpr int DD = 67;

// ws layout (bytes)
static constexpr size_t OFF_WXT   = 0;         // bf16 [1024][256]  W_x^T (x-part of 4 mats)
static constexpr size_t OFF_WQ    = 524288;    // i8   [512 thr][32 frags][16B] W_h^T quant, MFMA-B layout
static constexpr size_t OFF_SW    = 786432;    // f32  [1024] per-column scales
static constexpr size_t OFF_BIAS4 = 790528;    // f32  [1024] concat(b_ff1,b_ff2,b_ta,b_tb)
static constexpr size_t OFF_PWT   = 794624;    // bf16 [256][96] proj_W^T zero-padded
static constexpr size_t OFF_GW    = 843776;    // f32  [256] head_g*head_W
static constexpr size_t OFF_SCAL  = 844800;    // f32  [2]: S_gW, S_bW+head_bias
static constexpr size_t OFF_HST   = 845824;    // i32  [128][64] persisted packed-int8 h
static constexpr size_t OFF_FEAT  = 878592;    // bf16 [B*C][256] (feat, then reused as hseq)

// ---------------------------------------------------------------- prep
__global__ __launch_bounds__(256) void prep_kernel(
    const float* __restrict__ proj_W,
    const float* __restrict__ W_ff1, const float* __restrict__ b_ff1,
    const float* __restrict__ W_ff2, const float* __restrict__ b_ff2,
    const float* __restrict__ W_ta,  const float* __restrict__ b_ta,
    const float* __restrict__ W_tb,  const float* __restrict__ b_tb,
    const float* __restrict__ head_g, const float* __restrict__ head_b,
    const float* __restrict__ head_W, const float* __restrict__ head_bias,
    unsigned short* __restrict__ WxT, signed char* __restrict__ wq,
    float* __restrict__ sw, float* __restrict__ bias4,
    unsigned short* __restrict__ PWT, float* __restrict__ gW, float* __restrict__ scal)
{
  __shared__ float red[8];
  int bid = blockIdx.x, t = threadIdx.x;
  int wv = t >> 6, ln = t & 63;
  if (bid < 1024) {
    int J = bid, col = J & 255, which = J >> 8;
    const float* Wsrc = which == 0 ? W_ff1 : which == 1 ? W_ff2 : which == 2 ? W_ta : W_tb;
    const float* bsrc = which == 0 ? b_ff1 : which == 1 ? b_ff2 : which == 2 ? b_ta : b_tb;
    float w = Wsrc[t * 256 + col];          // x-part rows 0..255
    WxT[J * 256 + t] = f2bf(w);
    if (t == 0) bias4[J] = bsrc[col];
  } else if (bid < 2048) {
    int J = bid - 1024, col = J & 255, which = J >> 8;
    const float* Wsrc = which == 0 ? W_ff1 : which == 1 ? W_ff2 : which == 2 ? W_ta : W_tb;
    float w = Wsrc[(256 + t) * 256 + col];  // h-part rows 256..511, k = t
    float a = fabsf(w);
    for (int m = 32; m >= 1; m >>= 1) a = fmaxf(a, __shfl_xor(a, m, 64));
    if (ln == 0) red[wv] = a;
    __syncthreads();
    a = fmaxf(fmaxf(red[0], red[1]), fmaxf(red[2], red[3]));
    float scale = (a > 0.f) ? a * (1.f / 127.f) : 1.f;
    int q = (int)rintf(w / scale);
    q = q > 127 ? 127 : (q < -127 ? -127 : q);
    // MFMA-B layout: gate g=J>>8, col j=J&255, k=t.
    // wave = (g<<1)|(j>>7); lane = ((k&63)>>4)*16 + (j&15); col-tile tt=(j&127)>>4;
    // K-tile kt=k>>6; frag = tt*4+kt; byte-in-frag = k&15.
    {
      int g = which, j = col, k = t;
      int wavw = (g << 1) | (j >> 7);
      int lane = ((k & 63) >> 4) * 16 + (j & 15);
      int tt = (j & 127) >> 4;
      int kt = k >> 6;
      size_t dst = (size_t)(wavw * 64 + lane) * 512 + (size_t)(tt * 4 + kt) * 16 + (size_t)(k & 15);
      wq[dst] = (signed char)q;
    }
    if (t == 0) sw[J] = scale;
  } else {
    for (int idx = t; idx < 256 * 96; idx += 256) {
      int j = idx / 96, d = idx % 96;
      float v = (d < DD) ? proj_W[d * 256 + j] : 0.f;
      PWT[idx] = f2bf(v);
    }
    float gw = head_g[t] * head_W[t];
    gW[t] = gw;
    float bw = head_b[t] * head_W[t];
    float s1 = gw, s2 = bw;
    for (int m = 32; m >= 1; m >>= 1) { s1 += __shfl_xor(s1, m, 64); s2 += __shfl_xor(s2, m, 64); }
    if (ln == 0) { red[wv] = s1; red[4 + wv] = s2; }
    __syncthreads();
    if (t == 0) {
      scal[0] = red[0] + red[1] + red[2] + red[3];
      scal[1] = red[4] + red[5] + red[6] + red[7] + head_bias[0];
    }
  }
}

// ---------------------------------------------------------------- k2: x -> feat
__global__ __launch_bounds__(512) void feat_kernel(
    const float* __restrict__ x, const float* __restrict__ ln_in_g, const float* __restrict__ ln_in_b,
    const float* __restrict__ proj_b, const float* __restrict__ ln_p_g, const float* __restrict__ ln_p_b,
    const unsigned short* __restrict__ PWT, unsigned short* __restrict__ feat,
    int s0, int C, int cshift)
{
  __shared__ __align__(16) unsigned short XA[64 * 104];
  __shared__ __align__(16) unsigned short XB[256 * 96];
  __shared__ float partS[64][4], partQ[64][4], statM[64], statI[64];
  int tid = threadIdx.x, w = tid >> 6, lane = tid & 63;
  int r0 = blockIdx.x * 64;

  {
    float g1v = (lane < 67) ? ln_in_g[lane] : 0.f;
    float b1v = (lane < 67) ? ln_in_b[lane] : 0.f;
    float g2v = (lane < 3) ? ln_in_g[64 + lane] : 0.f;
    float b2v = (lane < 3) ? ln_in_b[64 + lane] : 0.f;
    for (int i = 0; i < 8; ++i) {
      int rl = w * 8 + i;
      int r = r0 + rl;
      int bb = r >> cshift, cs = r & (C - 1);
      const float* xr = x + (size_t)(bb * SS + s0 + cs) * DD;
      float v0 = (lane < 67) ? xr[lane] : 0.f;
      float v1 = (lane < 3) ? xr[64 + lane] : 0.f;
      float s = v0 + v1, q = v0 * v0 + v1 * v1;
      for (int m = 32; m >= 1; m >>= 1) { s += __shfl_xor(s, m, 64); q += __shfl_xor(q, m, 64); }
      float mean = s * (1.f / 67.f);
      float var = q * (1.f / 67.f) - mean * mean;
      float inv = rsqrtf(var + 1e-5f);
      float xn0 = (v0 - mean) * inv * g1v + b1v;
      float xn1 = (v1 - mean) * inv * g2v + b2v;
      XA[rl * 104 + lane] = (lane < 67) ? f2bf(xn0) : (unsigned short)0;
      if (lane < 40) XA[rl * 104 + 64 + lane] = (lane < 3) ? f2bf(xn1) : (unsigned short)0;
    }
  }
  {
    const unsigned int* src = (const unsigned int*)PWT;
    unsigned int* dst = (unsigned int*)XB;
    for (int idx = tid; idx < 256 * 48; idx += 512) dst[idx] = src[idx];
  }
  __syncthreads();

  int wm = w >> 2, wn = w & 3;
  f32x4 acc[2][4];
  #pragma unroll
  for (int mt = 0; mt < 2; ++mt)
    #pragma unroll
    for (int nt = 0; nt < 4; ++nt) acc[mt][nt] = (f32x4){0.f, 0.f, 0.f, 0.f};
  #pragma unroll
  for (int ks = 0; ks < 3; ++ks) {
    int k = ks * 32 + (lane >> 4) * 8;
    bf16x8 a[2], b[4];
    #pragma unroll
    for (int mt = 0; mt < 2; ++mt) {
      int row = wm * 32 + mt * 16 + (lane & 15);
      a[mt] = *reinterpret_cast<const bf16x8*>(&XA[row * 104 + k]);
    }
    #pragma unroll
    for (int nt = 0; nt < 4; ++nt) {
      int col = wn * 64 + nt * 16 + (lane & 15);
      b[nt] = *reinterpret_cast<const bf16x8*>(&XB[col * 96 + k]);
    }
    #pragma unroll
    for (int mt = 0; mt < 2; ++mt)
      #pragma unroll
      for (int nt = 0; nt < 4; ++nt)
        acc[mt][nt] = __builtin_amdgcn_mfma_f32_16x16x32_bf16(a[mt], b[nt], acc[mt][nt], 0, 0, 0);
  }
  #pragma unroll
  for (int nt = 0; nt < 4; ++nt) {
    int col = wn * 64 + nt * 16 + (lane & 15);
    float pb = proj_b[col];
    #pragma unroll
    for (int mt = 0; mt < 2; ++mt)
      #pragma unroll
      for (int r = 0; r < 4; ++r) acc[mt][nt][r] += pb;
  }
  #pragma unroll
  for (int mt = 0; mt < 2; ++mt) {
    #pragma unroll
    for (int r = 0; r < 4; ++r) {
      float s = 0.f, q = 0.f;
      #pragma unroll
      for (int nt = 0; nt < 4; ++nt) { float v = acc[mt][nt][r]; s += v; q += v * v; }
      for (int m = 1; m < 16; m <<= 1) { s += __shfl_xor(s, m, 16); q += __shfl_xor(q, m, 16); }
      if ((lane & 15) == 0) {
        int row = wm * 32 + mt * 16 + (lane >> 4) * 4 + r;
        partS[row][wn] = s; partQ[row][wn] = q;
      }
    }
  }
  __syncthreads();
  if (tid < 64) {
    float s = partS[tid][0] + partS[tid][1] + partS[tid][2] + partS[tid][3];
    float q = partQ[tid][0] + partQ[tid][1] + partQ[tid][2] + partQ[tid][3];
    float mean = s * (1.f / 256.f);
    float var = q * (1.f / 256.f) - mean * mean;
    statM[tid] = mean; statI[tid] = rsqrtf(var + 1e-5f);
  }
  __syncthreads();
  #pragma unroll
  for (int nt = 0; nt < 4; ++nt) {
    int col = wn * 64 + nt * 16 + (lane & 15);
    float gc = ln_p_g[col], bc = ln_p_b[col];
    #pragma unroll
    for (int mt = 0; mt < 2; ++mt)
      #pragma unroll
      for (int r = 0; r < 4; ++r) {
        int row = wm * 32 + mt * 16 + (lane >> 4) * 4 + r;
        float v = acc[mt][nt][r];
        float y = (v - statM[row]) * statI[row] * gc + bc;
        float sl = y * sigm(y);
        feat[(size_t)(r0 + row) * 256 + col] = f2bf(sl);
      }
  }
}

// ---------------------------------------------------------------- k3: pre = feat @ WxT + bias4
__global__ __launch_bounds__(256, 2) void gemm_kernel(
    const unsigned short* __restrict__ feat, const unsigned short* __restrict__ WxT,
    const float* __restrict__ bias4, unsigned short* __restrict__ pre)
{
  __shared__ __align__(16) unsigned short Abuf[128 * 64];
  __shared__ __align__(16) unsigned short Bbuf[128 * 64];
  int tid = threadIdx.x, w = tid >> 6, lane = tid & 63;
  int m0 = blockIdx.x * 128, n0 = blockIdx.y * 128;
  int wm = w >> 1, wn = w & 1;
  f32x4 acc[4][4];
  #pragma unroll
  for (int i = 0; i < 4; ++i)
    #pragma unroll
    for (int j = 0; j < 4; ++j) acc[i][j] = (f32x4){0.f, 0.f, 0.f, 0.f};

  #pragma unroll 1
  for (int ks = 0; ks < 4; ++ks) {
    int k0 = ks * 64;
    #pragma unroll
    for (int i = 0; i < 4; ++i) {
      int c = i * 256 + tid;
      int row = c >> 3, cc = c & 7;
      const unsigned short* ga = feat + (size_t)(m0 + row) * 256 + (k0 + cc * 8);
      const unsigned short* gb = WxT + (size_t)(n0 + row) * 256 + (k0 + cc * 8);
      char* la = (char*)Abuf + (size_t)(i * 256 + w * 64) * 16;
      char* lb = (char*)Bbuf + (size_t)(i * 256 + w * 64) * 16;
      GLD_LDS16(ga, la);
      GLD_LDS16(gb, lb);
    }
    __syncthreads();
    #pragma unroll
    for (int kk = 0; kk < 2; ++kk) {
      int k = kk * 32 + (lane >> 4) * 8;
      bf16x8 a[4], b[4];
      #pragma unroll
      for (int mt = 0; mt < 4; ++mt) {
        int row = wm * 64 + mt * 16 + (lane & 15);
        a[mt] = *reinterpret_cast<const bf16x8*>(&Abuf[row * 64 + k]);
      }
      #pragma unroll
      for (int nt = 0; nt < 4; ++nt) {
        int col = wn * 64 + nt * 16 + (lane & 15);
        b[nt] = *reinterpret_cast<const bf16x8*>(&Bbuf[col * 64 + k]);
      }
      #pragma unroll
      for (int mt = 0; mt < 4; ++mt)
        #pragma unroll
        for (int nt = 0; nt < 4; ++nt)
          acc[mt][nt] = __builtin_amdgcn_mfma_f32_16x16x32_bf16(a[mt], b[nt], acc[mt][nt], 0, 0, 0);
    }
    __syncthreads();
  }
  #pragma unroll
  for (int nt = 0; nt < 4; ++nt) {
    int col = n0 + wn * 64 + nt * 16 + (lane & 15);
    float bv = bias4[col];
    #pragma unroll
    for (int mt = 0; mt < 4; ++mt)
      #pragma unroll
      for (int r = 0; r < 4; ++r) {
        int row = m0 + wm * 64 + mt * 16 + (lane >> 4) * 4 + r;
        pre[(size_t)row * 1024 + col] = f2bf(acc[mt][nt][r] + bv);
      }
  }
}

// ---------------------------------------------------------------- k4: recurrent scan, 1 WG/batch
// Wave w owns gate-cols [w*128, (w+1)*128). B fragments (int8) live in physical AGPRs:
// frag(t,kt) at a[(t*4+kt)*4 .. +3], t=col-tile 0..7 (16 cols), kt=K-tile 0..3 (64 k).
// Per step: A = h broadcast (4x ds_read_b128), 32 MFMA i32_16x16x64_i8 with B=a[..];
// all D rows equal -> lanes 0..15 reg .x hold the 16 col sums. Gate phase: tid<256.
#define WRA(n, val) asm volatile("v_accvgpr_write_b32 a" #n ", %0" :: "v"(val) : "a" #n)
#define WR4(n0,n1,n2,n3, q) \
  do { WRA(n0,(q).x); WRA(n1,(q).y); WRA(n2,(q).z); WRA(n3,(q).w); } while (0)
#define MFMA_AB(acc, af, b0, b1) \
  asm volatile("v_mfma_i32_16x16x64_i8 %0, %1, a[" #b0 ":" #b1 "], %2" \
               : "=&v"(acc) : "v"(af), "v"(acc))

__global__ __attribute__((amdgpu_flat_work_group_size(512, 512)))
           __attribute__((amdgpu_waves_per_eu(2, 2)))
void scan_kernel(
    const unsigned short* __restrict__ pre, const float* __restrict__ dt,
    const signed char* __restrict__ wq, const float* __restrict__ sw,
    int* __restrict__ hstate, unsigned short* __restrict__ hseq, int s0, int C)
{
  __shared__ int hq2[2][64];
  __shared__ int gsh[1024];
  int tid = threadIdx.x, w = tid >> 6, l = tid & 63;
  int b = blockIdx.x;

  // stage 128 weight dwords (32 B-fragments) into physical AGPRs a0..a127
  {
    const int4* wp = (const int4*)(wq + (size_t)tid * 512);
    int4 q0, q1, q2, q3, q4, q5, q6, q7;
    q0=wp[0]; q1=wp[1]; q2=wp[2]; q3=wp[3]; q4=wp[4]; q5=wp[5]; q6=wp[6]; q7=wp[7];
    WR4(0,1,2,3,q0);     WR4(4,5,6,7,q1);     WR4(8,9,10,11,q2);    WR4(12,13,14,15,q3);
    WR4(16,17,18,19,q4); WR4(20,21,22,23,q5); WR4(24,25,26,27,q6);  WR4(28,29,30,31,q7);
    q0=wp[8]; q1=wp[9]; q2=wp[10]; q3=wp[11]; q4=wp[12]; q5=wp[13]; q6=wp[14]; q7=wp[15];
    WR4(32,33,34,35,q0); WR4(36,37,38,39,q1); WR4(40,41,42,43,q2);  WR4(44,45,46,47,q3);
    WR4(48,49,50,51,q4); WR4(52,53,54,55,q5); WR4(56,57,58,59,q6);  WR4(60,61,62,63,q7);
    q0=wp[16]; q1=wp[17]; q2=wp[18]; q3=wp[19]; q4=wp[20]; q5=wp[21]; q6=wp[22]; q7=wp[23];
    WR4(64,65,66,67,q0); WR4(68,69,70,71,q1); WR4(72,73,74,75,q2);  WR4(76,77,78,79,q3);
    WR4(80,81,82,83,q4); WR4(84,85,86,87,q5); WR4(88,89,90,91,q6);  WR4(92,93,94,95,q7);
    q0=wp[24]; q1=wp[25]; q2=wp[26]; q3=wp[27]; q4=wp[28]; q5=wp[29]; q6=wp[30]; q7=wp[31];
    WR4(96,97,98,99,q0);   WR4(100,101,102,103,q1); WR4(104,105,106,107,q2); WR4(108,109,110,111,q3);
    WR4(112,113,114,115,q4); WR4(116,117,118,119,q5); WR4(120,121,122,123,q6); WR4(124,125,126,127,q7);
  }

  // gate-phase per-thread constants (tid<256: j0 = tid)
  float sc0 = 0.f, sc1 = 0.f, sc2 = 0.f, sc3 = 0.f;
  unsigned short pu0 = 0, pu1 = 0, pu2 = 0, pu3 = 0;
  float dtc = 0.f;
  const unsigned short* preB = pre + (size_t)b * C * 1024;
  unsigned short* hsB = hseq + (size_t)b * C * 256;
  if (tid < 256) {
    sc0 = sw[tid]       * (1.f / 127.f);
    sc1 = sw[256 + tid] * (1.f / 127.f);
    sc2 = sw[512 + tid] * (1.f / 127.f);
    sc3 = sw[768 + tid] * (1.f / 127.f);
    pu0 = preB[tid]; pu1 = preB[256 + tid]; pu2 = preB[512 + tid]; pu3 = preB[768 + tid];
    dtc = dt[b * SS + s0] * 10.f;
  }

  if (tid < 64) hq2[0][tid] = (s0 == 0) ? 0 : hstate[b * 64 + tid];
  int cur = 0;
  __syncthreads();

  for (int cs = 0; cs < C; ++cs) {
    // A fragments: h broadcast, 16 bytes per 16-lane group per K-tile
    const char* hb = (const char*)hq2[cur];
    int aoff = (l >> 4) << 4;
    i32x4 A0 = *reinterpret_cast<const i32x4*>(hb + 0 * 64 + aoff);
    i32x4 A1 = *reinterpret_cast<const i32x4*>(hb + 1 * 64 + aoff);
    i32x4 A2 = *reinterpret_cast<const i32x4*>(hb + 2 * 64 + aoff);
    i32x4 A3 = *reinterpret_cast<const i32x4*>(hb + 3 * 64 + aoff);
    i32x4 c0 = {0,0,0,0}, c1 = {0,0,0,0}, c2 = {0,0,0,0}, c3 = {0,0,0,0};
    i32x4 c4 = {0,0,0,0}, c5 = {0,0,0,0}, c6 = {0,0,0,0}, c7 = {0,0,0,0};
    // kt=0
    MFMA_AB(c0, A0,   0,   3); MFMA_AB(c1, A0,  16,  19); MFMA_AB(c2, A0,  32,  35); MFMA_AB(c3, A0,  48,  51);
    MFMA_AB(c4, A0,  64,  67); MFMA_AB(c5, A0,  80,  83); MFMA_AB(c6, A0,  96,  99); MFMA_AB(c7, A0, 112, 115);
    // kt=1
    MFMA_AB(c0, A1,   4,   7); MFMA_AB(c1, A1,  20,  23); MFMA_AB(c2, A1,  36,  39); MFMA_AB(c3, A1,  52,  55);
    MFMA_AB(c4, A1,  68,  71); MFMA_AB(c5, A1,  84,  87); MFMA_AB(c6, A1, 100, 103); MFMA_AB(c7, A1, 116, 119);
    // kt=2
    MFMA_AB(c0, A2,   8,  11); MFMA_AB(c1, A2,  24,  27); MFMA_AB(c2, A2,  40,  43); MFMA_AB(c3, A2,  56,  59);
    MFMA_AB(c4, A2,  72,  75); MFMA_AB(c5, A2,  88,  91); MFMA_AB(c6, A2, 104, 107); MFMA_AB(c7, A2, 120, 123);
    // kt=3
    MFMA_AB(c0, A3,  12,  15); MFMA_AB(c1, A3,  28,  31); MFMA_AB(c2, A3,  44,  47); MFMA_AB(c3, A3,  60,  63);
    MFMA_AB(c4, A3,  76,  79); MFMA_AB(c5, A3,  92,  95); MFMA_AB(c6, A3, 108, 111); MFMA_AB(c7, A3, 124, 127);
    asm volatile("s_nop 7\n\ts_nop 7\n\ts_nop 7");   // MFMA-D -> mem-read hazard margin
    if (l < 16) {
      int p = w * 128 + l;
      gsh[p      ] = c0.x; gsh[p +  16] = c1.x; gsh[p +  32] = c2.x; gsh[p +  48] = c3.x;
      gsh[p +  64] = c4.x; gsh[p +  80] = c5.x; gsh[p +  96] = c6.x; gsh[p + 112] = c7.x;
    }
    __syncthreads();
    if (tid < 256) {
      int d0 = gsh[tid], d1 = gsh[256 + tid], d2 = gsh[512 + tid], d3 = gsh[768 + tid];
      float g0 = (float)d0 * sc0 + bf2f(pu0);
      float g1 = (float)d1 * sc1 + bf2f(pu1);
      float g2 = (float)d2 * sc2 + bf2f(pu2);
      float g3 = (float)d3 * sc3 + bf2f(pu3);
      float f1 = tanh_f(g0), f2 = tanh_f(g1);
      float ti = sigm(g2 * dtc + g3);
      float h = f1 + ti * (f2 - f1);
      int q = (int)rintf(h * 127.f);
      q = q > 127 ? 127 : (q < -127 ? -127 : q);
      ((signed char*)hq2[cur ^ 1])[tid] = (signed char)q;
      hsB[(size_t)cs * 256 + tid] = f2bf(h);
      if (cs + 1 < C) {   // prefetch next step
        const unsigned short* pn = preB + (size_t)(cs + 1) * 1024;
        pu0 = pn[tid]; pu1 = pn[256 + tid]; pu2 = pn[512 + tid]; pu3 = pn[768 + tid];
        dtc = dt[b * SS + s0 + cs + 1] * 10.f;
      }
    }
    cur ^= 1;
    __syncthreads();
  }
  if (tid < 64) hstate[b * 64 + tid] = hq2[cur][tid];
}

// ---------------------------------------------------------------- k5: head from hseq
__global__ __launch_bounds__(256) void head_kernel(
    const unsigned short* __restrict__ hseq, const float* __restrict__ gW,
    const float* __restrict__ scal, float* __restrict__ out, int s0, int C, int cshift)
{
  int tid = threadIdx.x, wv = tid >> 6, l = tid & 63;
  int row = blockIdx.x * 4 + wv;                 // row in [0, B*C)
  const unsigned short* hr = hseq + (size_t)row * 256 + l * 4;
  ushort4 u = *reinterpret_cast<const ushort4*>(hr);
  float4 gw = *reinterpret_cast<const float4*>(gW + l * 4);
  float v0 = bf2f(u.x), v1 = bf2f(u.y), v2 = bf2f(u.z), v3 = bf2f(u.w);
  float s1 = v0 + v1 + v2 + v3;
  float s2 = v0 * v0 + v1 * v1 + v2 * v2 + v3 * v3;
  float s3 = v0 * gw.x + v1 * gw.y + v2 * gw.z + v3 * gw.w;
  for (int m = 32; m >= 1; m >>= 1) {
    s1 += __shfl_xor(s1, m, 64); s2 += __shfl_xor(s2, m, 64); s3 += __shfl_xor(s3, m, 64);
  }
  if (l == 0) {
    float mean = s1 * (1.f / 256.f);
    float var = s2 * (1.f / 256.f) - mean * mean;
    float inv = rsqrtf(var + 1e-5f);
    int b = row >> cshift, cs = row & (C - 1);
    out[(size_t)b * SS + s0 + cs] = inv * (s3 - mean * scal[0]) + scal[1];
  }
}

// ---------------------------------------------------------------- launch
extern "C" void kernel_launch(void* const* d_in, const int* in_sizes, int n_in,
                              void* d_out, int out_size, void* d_ws, size_t ws_size,
                              hipStream_t stream)
{
  (void)in_sizes; (void)n_in; (void)out_size;
  const float* x        = (const float*)d_in[0];
  const float* dt       = (const float*)d_in[1];
  const float* ln_in_g  = (const float*)d_in[2];
  const float* ln_in_b  = (const float*)d_in[3];
  const float* proj_W   = (const float*)d_in[4];
  const float* proj_b   = (const float*)d_in[5];
  const float* ln_p_g   = (const float*)d_in[6];
  const float* ln_p_b   = (const float*)d_in[7];
  const float* W_ff1    = (const float*)d_in[8];
  const float* b_ff1    = (const float*)d_in[9];
  const float* W_ff2    = (const float*)d_in[10];
  const float* b_ff2    = (const float*)d_in[11];
  const float* W_ta     = (const float*)d_in[12];
  const float* b_ta     = (const float*)d_in[13];
  const float* W_tb     = (const float*)d_in[14];
  const float* b_tb     = (const float*)d_in[15];
  const float* head_g   = (const float*)d_in[16];
  const float* head_b   = (const float*)d_in[17];
  const float* head_W   = (const float*)d_in[18];
  const float* head_bias= (const float*)d_in[19];

  char* ws = (char*)d_ws;
  unsigned short* WxT = (unsigned short*)(ws + OFF_WXT);
  signed char* wq     = (signed char*)(ws + OFF_WQ);
  float* sw           = (float*)(ws + OFF_SW);
  float* bias4        = (float*)(ws + OFF_BIAS4);
  unsigned short* PWT = (unsigned short*)(ws + OFF_PWT);
  float* gWv          = (float*)(ws + OFF_GW);
  float* scal         = (float*)(ws + OFF_SCAL);
  int* hstate         = (int*)(ws + OFF_HST);

  int C = 16;
  for (int c = 2048; c >= 16; c >>= 1) {
    size_t need = OFF_FEAT + (size_t)c * 65536 + (size_t)c * 262144;
    if (need <= ws_size) { C = c; break; }
  }
  unsigned short* featb = (unsigned short*)(ws + OFF_FEAT);   // feat, then hseq
  unsigned short* preb  = (unsigned short*)(ws + OFF_FEAT + (size_t)C * 65536);
  int cshift = 31 - __builtin_clz((unsigned)C);

  prep_kernel<<<2049, 256, 0, stream>>>(proj_W, W_ff1, b_ff1, W_ff2, b_ff2, W_ta, b_ta, W_tb, b_tb,
                                        head_g, head_b, head_W, head_bias,
                                        WxT, wq, sw, bias4, PWT, gWv, scal);
  int nch = SS / C;
  for (int ch = 0; ch < nch; ++ch) {
    int s0 = ch * C;
    feat_kernel<<<dim3(BB * C / 64), 512, 0, stream>>>(x, ln_in_g, ln_in_b, proj_b, ln_p_g, ln_p_b,
                                                       PWT, featb, s0, C, cshift);
    gemm_kernel<<<dim3(BB * C / 128, 8), 256, 0, stream>>>(featb, WxT, bias4, preb);
    scan_kernel<<<dim3(BB), 512, 0, stream>>>(preb, dt, wq, sw, hstate, featb, s0, C);
    head_kernel<<<dim3(BB * C / 4), 256, 0, stream>>>(featb, gWv, scal, (float*)d_out, s0, C, cshift);
  }
}

// Round 10
// 2569.308 us; speedup vs baseline: 1.5422x; 1.0597x over previous
//
#include <hip/hip_runtime.h>

// StructLNN: LN(67) -> Linear(67,256)+LN+SiLU -> CfC scan (2048 steps) -> LN head -> [B,S,1]
//   prep: repack weights (W_x^T bf16 for GEMM; W_h int8 quantized, repacked as per-wave
//         MFMA B-fragments: wave w owns cols [w*32,(w+1)*32) x ALL 4 gates)
//   k2 feat_kernel: input LN + MFMA proj + LN + SiLU -> feat bf16
//   k3 gemm_kernel: pre = feat @ W_x^T + bias4 (bf16 MFMA)
//   k4 scan_kernel: 1 WG/batch, 8 waves. Weights in PHYSICAL AGPRs a0..a127; per step
//      32 v_mfma_i32_16x16x64_i8 per wave, B=a[N:N+3] (MFMA reads AGPRs; VOP3P can't - r7).
//      A = h broadcast; all D rows equal. Fragments = (gate,col-tile) pairs IN-WAVE ->
//      gate phase reads own c regs (r9's gsh round-trip + 2nd barrier eliminated).
//      ONE barrier/step; double-buffered hq2. Integer-exact (r8/r9 absmax 0.015625).
//      History: r2-r5 RA spills any compiler-managed weights (625us L2 floor);
//      r6/r8 accvgpr_read+sdot VALU-bound (858us); r9 MFMA 2-barrier (579us, 2700cyc/step
//      = 1280 MFMA-pipe floor + 1400 barrier/gsh overhead <- this round removes the latter).
//   k5 head_kernel: folded LN+head over hseq (memory-bound).

typedef __bf16 bf16x8 __attribute__((ext_vector_type(8)));
typedef float f32x4 __attribute__((ext_vector_type(4)));
typedef int i32x4 __attribute__((ext_vector_type(4)));

#define DEVFN static __device__ __forceinline__

DEVFN float bf2f(unsigned short u){ return __uint_as_float(((unsigned)u) << 16); }
DEVFN unsigned short f2bf(float f){
  unsigned x = __float_as_uint(f);
  return (unsigned short)((x + 0x7FFFu + ((x >> 16) & 1u)) >> 16);
}
DEVFN float sigm(float x){ return 1.f / (1.f + __expf(-x)); }
DEVFN float tanh_f(float x){ return 1.f - 2.f / (__expf(2.f * x) + 1.f); }

#define GLD_LDS16(g, l) \
  __builtin_amdgcn_global_load_lds((const __attribute__((address_space(1))) void*)(g), \
                                   (__attribute__((address_space(3))) void*)(l), 16, 0, 0)

static constexpr int BB = 128;
static constexpr int SS = 2048;
static constexpr int DD = 67;

// ws layout (bytes)
static constexpr size_t OFF_WXT   = 0;         // bf16 [1024][256]  W_x^T (x-part of 4 mats)
static constexpr size_t OFF_WQ    = 524288;    // i8   [512 thr][32 frags][16B] W_h^T quant, MFMA-B layout
static constexpr size_t OFF_SW    = 786432;    // f32  [1024] per-column scales
static constexpr size_t OFF_BIAS4 = 790528;    // f32  [1024] concat(b_ff1,b_ff2,b_ta,b_tb)
static constexpr size_t OFF_PWT   = 794624;    // bf16 [256][96] proj_W^T zero-padded
static constexpr size_t OFF_GW    = 843776;    // f32  [256] head_g*head_W
static constexpr size_t OFF_SCAL  = 844800;    // f32  [2]: S_gW, S_bW+head_bias
static constexpr size_t OFF_HST   = 845824;    // i32  [128][64] persisted packed-int8 h
static constexpr size_t OFF_FEAT  = 878592;    // bf16 [B*C][256] (feat, then reused as hseq)

// ---------------------------------------------------------------- prep
__global__ __launch_bounds__(256) void prep_kernel(
    const float* __restrict__ proj_W,
    const float* __restrict__ W_ff1, const float* __restrict__ b_ff1,
    const float* __restrict__ W_ff2, const float* __restrict__ b_ff2,
    const float* __restrict__ W_ta,  const float* __restrict__ b_ta,
    const float* __restrict__ W_tb,  const float* __restrict__ b_tb,
    const float* __restrict__ head_g, const float* __restrict__ head_b,
    const float* __restrict__ head_W, const float* __restrict__ head_bias,
    unsigned short* __restrict__ WxT, signed char* __restrict__ wq,
    float* __restrict__ sw, float* __restrict__ bias4,
    unsigned short* __restrict__ PWT, float* __restrict__ gW, float* __restrict__ scal)
{
  __shared__ float red[8];
  int bid = blockIdx.x, t = threadIdx.x;
  int wv = t >> 6, ln = t & 63;
  if (bid < 1024) {
    int J = bid, col = J & 255, which = J >> 8;
    const float* Wsrc = which == 0 ? W_ff1 : which == 1 ? W_ff2 : which == 2 ? W_ta : W_tb;
    const float* bsrc = which == 0 ? b_ff1 : which == 1 ? b_ff2 : which == 2 ? b_ta : b_tb;
    float w = Wsrc[t * 256 + col];          // x-part rows 0..255
    WxT[J * 256 + t] = f2bf(w);
    if (t == 0) bias4[J] = bsrc[col];
  } else if (bid < 2048) {
    int J = bid - 1024, col = J & 255, which = J >> 8;
    const float* Wsrc = which == 0 ? W_ff1 : which == 1 ? W_ff2 : which == 2 ? W_ta : W_tb;
    float w = Wsrc[(256 + t) * 256 + col];  // h-part rows 256..511, k = t
    float a = fabsf(w);
    for (int m = 32; m >= 1; m >>= 1) a = fmaxf(a, __shfl_xor(a, m, 64));
    if (ln == 0) red[wv] = a;
    __syncthreads();
    a = fmaxf(fmaxf(red[0], red[1]), fmaxf(red[2], red[3]));
    float scale = (a > 0.f) ? a * (1.f / 127.f) : 1.f;
    int q = (int)rintf(w / scale);
    q = q > 127 ? 127 : (q < -127 ? -127 : q);
    // MFMA-B layout (in-wave gates): gate g, col j, k.
    // wave = j>>5; tt=(j>>4)&1; frag f=(g*2+tt)*4+(k>>6);
    // lane = ((k&63)>>4)*16 + (j&15); byte = k&15.
    {
      int g = which, j = col, k = t;
      int wavw = j >> 5;
      int lane = ((k & 63) >> 4) * 16 + (j & 15);
      int tt = (j >> 4) & 1;
      int f = (g * 2 + tt) * 4 + (k >> 6);
      size_t dst = (size_t)(wavw * 64 + lane) * 512 + (size_t)f * 16 + (size_t)(k & 15);
      wq[dst] = (signed char)q;
    }
    if (t == 0) sw[J] = scale;
  } else {
    for (int idx = t; idx < 256 * 96; idx += 256) {
      int j = idx / 96, d = idx % 96;
      float v = (d < DD) ? proj_W[d * 256 + j] : 0.f;
      PWT[idx] = f2bf(v);
    }
    float gw = head_g[t] * head_W[t];
    gW[t] = gw;
    float bw = head_b[t] * head_W[t];
    float s1 = gw, s2 = bw;
    for (int m = 32; m >= 1; m >>= 1) { s1 += __shfl_xor(s1, m, 64); s2 += __shfl_xor(s2, m, 64); }
    if (ln == 0) { red[wv] = s1; red[4 + wv] = s2; }
    __syncthreads();
    if (t == 0) {
      scal[0] = red[0] + red[1] + red[2] + red[3];
      scal[1] = red[4] + red[5] + red[6] + red[7] + head_bias[0];
    }
  }
}

// ---------------------------------------------------------------- k2: x -> feat
__global__ __launch_bounds__(512) void feat_kernel(
    const float* __restrict__ x, const float* __restrict__ ln_in_g, const float* __restrict__ ln_in_b,
    const float* __restrict__ proj_b, const float* __restrict__ ln_p_g, const float* __restrict__ ln_p_b,
    const unsigned short* __restrict__ PWT, unsigned short* __restrict__ feat,
    int s0, int C, int cshift)
{
  __shared__ __align__(16) unsigned short XA[64 * 104];
  __shared__ __align__(16) unsigned short XB[256 * 96];
  __shared__ float partS[64][4], partQ[64][4], statM[64], statI[64];
  int tid = threadIdx.x, w = tid >> 6, lane = tid & 63;
  int r0 = blockIdx.x * 64;

  {
    float g1v = (lane < 67) ? ln_in_g[lane] : 0.f;
    float b1v = (lane < 67) ? ln_in_b[lane] : 0.f;
    float g2v = (lane < 3) ? ln_in_g[64 + lane] : 0.f;
    float b2v = (lane < 3) ? ln_in_b[64 + lane] : 0.f;
    for (int i = 0; i < 8; ++i) {
      int rl = w * 8 + i;
      int r = r0 + rl;
      int bb = r >> cshift, cs = r & (C - 1);
      const float* xr = x + (size_t)(bb * SS + s0 + cs) * DD;
      float v0 = (lane < 67) ? xr[lane] : 0.f;
      float v1 = (lane < 3) ? xr[64 + lane] : 0.f;
      float s = v0 + v1, q = v0 * v0 + v1 * v1;
      for (int m = 32; m >= 1; m >>= 1) { s += __shfl_xor(s, m, 64); q += __shfl_xor(q, m, 64); }
      float mean = s * (1.f / 67.f);
      float var = q * (1.f / 67.f) - mean * mean;
      float inv = rsqrtf(var + 1e-5f);
      float xn0 = (v0 - mean) * inv * g1v + b1v;
      float xn1 = (v1 - mean) * inv * g2v + b2v;
      XA[rl * 104 + lane] = (lane < 67) ? f2bf(xn0) : (unsigned short)0;
      if (lane < 40) XA[rl * 104 + 64 + lane] = (lane < 3) ? f2bf(xn1) : (unsigned short)0;
    }
  }
  {
    const unsigned int* src = (const unsigned int*)PWT;
    unsigned int* dst = (unsigned int*)XB;
    for (int idx = tid; idx < 256 * 48; idx += 512) dst[idx] = src[idx];
  }
  __syncthreads();

  int wm = w >> 2, wn = w & 3;
  f32x4 acc[2][4];
  #pragma unroll
  for (int mt = 0; mt < 2; ++mt)
    #pragma unroll
    for (int nt = 0; nt < 4; ++nt) acc[mt][nt] = (f32x4){0.f, 0.f, 0.f, 0.f};
  #pragma unroll
  for (int ks = 0; ks < 3; ++ks) {
    int k = ks * 32 + (lane >> 4) * 8;
    bf16x8 a[2], b[4];
    #pragma unroll
    for (int mt = 0; mt < 2; ++mt) {
      int row = wm * 32 + mt * 16 + (lane & 15);
      a[mt] = *reinterpret_cast<const bf16x8*>(&XA[row * 104 + k]);
    }
    #pragma unroll
    for (int nt = 0; nt < 4; ++nt) {
      int col = wn * 64 + nt * 16 + (lane & 15);
      b[nt] = *reinterpret_cast<const bf16x8*>(&XB[col * 96 + k]);
    }
    #pragma unroll
    for (int mt = 0; mt < 2; ++mt)
      #pragma unroll
      for (int nt = 0; nt < 4; ++nt)
        acc[mt][nt] = __builtin_amdgcn_mfma_f32_16x16x32_bf16(a[mt], b[nt], acc[mt][nt], 0, 0, 0);
  }
  #pragma unroll
  for (int nt = 0; nt < 4; ++nt) {
    int col = wn * 64 + nt * 16 + (lane & 15);
    float pb = proj_b[col];
    #pragma unroll
    for (int mt = 0; mt < 2; ++mt)
      #pragma unroll
      for (int r = 0; r < 4; ++r) acc[mt][nt][r] += pb;
  }
  #pragma unroll
  for (int mt = 0; mt < 2; ++mt) {
    #pragma unroll
    for (int r = 0; r < 4; ++r) {
      float s = 0.f, q = 0.f;
      #pragma unroll
      for (int nt = 0; nt < 4; ++nt) { float v = acc[mt][nt][r]; s += v; q += v * v; }
      for (int m = 1; m < 16; m <<= 1) { s += __shfl_xor(s, m, 16); q += __shfl_xor(q, m, 16); }
      if ((lane & 15) == 0) {
        int row = wm * 32 + mt * 16 + (lane >> 4) * 4 + r;
        partS[row][wn] = s; partQ[row][wn] = q;
      }
    }
  }
  __syncthreads();
  if (tid < 64) {
    float s = partS[tid][0] + partS[tid][1] + partS[tid][2] + partS[tid][3];
    float q = partQ[tid][0] + partQ[tid][1] + partQ[tid][2] + partQ[tid][3];
    float mean = s * (1.f / 256.f);
    float var = q * (1.f / 256.f) - mean * mean;
    statM[tid] = mean; statI[tid] = rsqrtf(var + 1e-5f);
  }
  __syncthreads();
  #pragma unroll
  for (int nt = 0; nt < 4; ++nt) {
    int col = wn * 64 + nt * 16 + (lane & 15);
    float gc = ln_p_g[col], bc = ln_p_b[col];
    #pragma unroll
    for (int mt = 0; mt < 2; ++mt)
      #pragma unroll
      for (int r = 0; r < 4; ++r) {
        int row = wm * 32 + mt * 16 + (lane >> 4) * 4 + r;
        float v = acc[mt][nt][r];
        float y = (v - statM[row]) * statI[row] * gc + bc;
        float sl = y * sigm(y);
        feat[(size_t)(r0 + row) * 256 + col] = f2bf(sl);
      }
  }
}

// ---------------------------------------------------------------- k3: pre = feat @ WxT + bias4
__global__ __launch_bounds__(256, 2) void gemm_kernel(
    const unsigned short* __restrict__ feat, const unsigned short* __restrict__ WxT,
    const float* __restrict__ bias4, unsigned short* __restrict__ pre)
{
  __shared__ __align__(16) unsigned short Abuf[128 * 64];
  __shared__ __align__(16) unsigned short Bbuf[128 * 64];
  int tid = threadIdx.x, w = tid >> 6, lane = tid & 63;
  int m0 = blockIdx.x * 128, n0 = blockIdx.y * 128;
  int wm = w >> 1, wn = w & 1;
  f32x4 acc[4][4];
  #pragma unroll
  for (int i = 0; i < 4; ++i)
    #pragma unroll
    for (int j = 0; j < 4; ++j) acc[i][j] = (f32x4){0.f, 0.f, 0.f, 0.f};

  #pragma unroll 1
  for (int ks = 0; ks < 4; ++ks) {
    int k0 = ks * 64;
    #pragma unroll
    for (int i = 0; i < 4; ++i) {
      int c = i * 256 + tid;
      int row = c >> 3, cc = c & 7;
      const unsigned short* ga = feat + (size_t)(m0 + row) * 256 + (k0 + cc * 8);
      const unsigned short* gb = WxT + (size_t)(n0 + row) * 256 + (k0 + cc * 8);
      char* la = (char*)Abuf + (size_t)(i * 256 + w * 64) * 16;
      char* lb = (char*)Bbuf + (size_t)(i * 256 + w * 64) * 16;
      GLD_LDS16(ga, la);
      GLD_LDS16(gb, lb);
    }
    __syncthreads();
    #pragma unroll
    for (int kk = 0; kk < 2; ++kk) {
      int k = kk * 32 + (lane >> 4) * 8;
      bf16x8 a[4], b[4];
      #pragma unroll
      for (int mt = 0; mt < 4; ++mt) {
        int row = wm * 64 + mt * 16 + (lane & 15);
        a[mt] = *reinterpret_cast<const bf16x8*>(&Abuf[row * 64 + k]);
      }
      #pragma unroll
      for (int nt = 0; nt < 4; ++nt) {
        int col = wn * 64 + nt * 16 + (lane & 15);
        b[nt] = *reinterpret_cast<const bf16x8*>(&Bbuf[col * 64 + k]);
      }
      #pragma unroll
      for (int mt = 0; mt < 4; ++mt)
        #pragma unroll
        for (int nt = 0; nt < 4; ++nt)
          acc[mt][nt] = __builtin_amdgcn_mfma_f32_16x16x32_bf16(a[mt], b[nt], acc[mt][nt], 0, 0, 0);
    }
    __syncthreads();
  }
  #pragma unroll
  for (int nt = 0; nt < 4; ++nt) {
    int col = n0 + wn * 64 + nt * 16 + (lane & 15);
    float bv = bias4[col];
    #pragma unroll
    for (int mt = 0; mt < 4; ++mt)
      #pragma unroll
      for (int r = 0; r < 4; ++r) {
        int row = m0 + wm * 64 + mt * 16 + (lane >> 4) * 4 + r;
        pre[(size_t)row * 1024 + col] = f2bf(acc[mt][nt][r] + bv);
      }
  }
}

// ---------------------------------------------------------------- k4: recurrent scan, 1 WG/batch
// Wave w owns cols [w*32,(w+1)*32) x all 4 gates. B fragments in physical AGPRs:
// frag f=(g*2+tt) at a[f*16+kt*4 .. +3]. Per step: A = h broadcast, 32 MFMA; gate phase
// reads own c regs (no cross-wave exchange); ONE barrier/step via double-buffered hq2.
#define WRA(n, val) asm volatile("v_accvgpr_write_b32 a" #n ", %0" :: "v"(val) : "a" #n)
#define WR4(n0,n1,n2,n3, q) \
  do { WRA(n0,(q).x); WRA(n1,(q).y); WRA(n2,(q).z); WRA(n3,(q).w); } while (0)
#define MFMA_AB(acc, af, b0, b1) \
  asm volatile("v_mfma_i32_16x16x64_i8 %0, %1, a[" #b0 ":" #b1 "], %2" \
               : "=&v"(acc) : "v"(af), "v"(acc))

__global__ __attribute__((amdgpu_flat_work_group_size(512, 512)))
           __attribute__((amdgpu_waves_per_eu(2, 2)))
void scan_kernel(
    const unsigned short* __restrict__ pre, const float* __restrict__ dt,
    const signed char* __restrict__ wq, const float* __restrict__ sw,
    int* __restrict__ hstate, unsigned short* __restrict__ hseq, int s0, int C)
{
  __shared__ __align__(16) signed char hq2[2][256];
  int tid = threadIdx.x, w = tid >> 6, l = tid & 63;
  int b = blockIdx.x;

  // stage 128 weight dwords (32 B-fragments) into physical AGPRs a0..a127
  {
    const int4* wp = (const int4*)(wq + (size_t)tid * 512);
    int4 q0, q1, q2, q3, q4, q5, q6, q7;
    q0=wp[0]; q1=wp[1]; q2=wp[2]; q3=wp[3]; q4=wp[4]; q5=wp[5]; q6=wp[6]; q7=wp[7];
    WR4(0,1,2,3,q0);     WR4(4,5,6,7,q1);     WR4(8,9,10,11,q2);    WR4(12,13,14,15,q3);
    WR4(16,17,18,19,q4); WR4(20,21,22,23,q5); WR4(24,25,26,27,q6);  WR4(28,29,30,31,q7);
    q0=wp[8]; q1=wp[9]; q2=wp[10]; q3=wp[11]; q4=wp[12]; q5=wp[13]; q6=wp[14]; q7=wp[15];
    WR4(32,33,34,35,q0); WR4(36,37,38,39,q1); WR4(40,41,42,43,q2);  WR4(44,45,46,47,q3);
    WR4(48,49,50,51,q4); WR4(52,53,54,55,q5); WR4(56,57,58,59,q6);  WR4(60,61,62,63,q7);
    q0=wp[16]; q1=wp[17]; q2=wp[18]; q3=wp[19]; q4=wp[20]; q5=wp[21]; q6=wp[22]; q7=wp[23];
    WR4(64,65,66,67,q0); WR4(68,69,70,71,q1); WR4(72,73,74,75,q2);  WR4(76,77,78,79,q3);
    WR4(80,81,82,83,q4); WR4(84,85,86,87,q5); WR4(88,89,90,91,q6);  WR4(92,93,94,95,q7);
    q0=wp[24]; q1=wp[25]; q2=wp[26]; q3=wp[27]; q4=wp[28]; q5=wp[29]; q6=wp[30]; q7=wp[31];
    WR4(96,97,98,99,q0);   WR4(100,101,102,103,q1); WR4(104,105,106,107,q2); WR4(108,109,110,111,q3);
    WR4(112,113,114,115,q4); WR4(116,117,118,119,q5); WR4(120,121,122,123,q6); WR4(124,125,126,127,q7);
  }

  // gate-phase lanes: lg<2; tt=lg; col j = w*32 + tt*16 + (l&15)
  int lg = l >> 4;
  int tt = lg & 1;
  bool gact = (lg < 2);
  int j = w * 32 + tt * 16 + (l & 15);

  float sc0 = 0.f, sc1 = 0.f, sc2 = 0.f, sc3 = 0.f;
  unsigned short pu0 = 0, pu1 = 0, pu2 = 0, pu3 = 0;
  float dtc = 0.f;
  const unsigned short* preB = pre + (size_t)b * C * 1024;
  unsigned short* hsB = hseq + (size_t)b * C * 256;
  if (gact) {
    sc0 = sw[j]       * (1.f / 127.f);
    sc1 = sw[256 + j] * (1.f / 127.f);
    sc2 = sw[512 + j] * (1.f / 127.f);
    sc3 = sw[768 + j] * (1.f / 127.f);
    pu0 = preB[j]; pu1 = preB[256 + j]; pu2 = preB[512 + j]; pu3 = preB[768 + j];
    dtc = dt[b * SS + s0] * 10.f;
  }

  if (tid < 64) ((int*)hq2[0])[tid] = (s0 == 0) ? 0 : hstate[b * 64 + tid];
  int cur = 0;
  __syncthreads();

  for (int cs = 0; cs < C; ++cs) {
    // A fragments: h broadcast, 16 bytes per 16-lane group per K-tile
    const signed char* hb = hq2[cur];
    int aoff = lg << 4;
    i32x4 A0 = *reinterpret_cast<const i32x4*>(hb + 0 * 64 + aoff);
    i32x4 A1 = *reinterpret_cast<const i32x4*>(hb + 1 * 64 + aoff);
    i32x4 A2 = *reinterpret_cast<const i32x4*>(hb + 2 * 64 + aoff);
    i32x4 A3 = *reinterpret_cast<const i32x4*>(hb + 3 * 64 + aoff);
    i32x4 c0 = {0,0,0,0}, c1 = {0,0,0,0}, c2 = {0,0,0,0}, c3 = {0,0,0,0};
    i32x4 c4 = {0,0,0,0}, c5 = {0,0,0,0}, c6 = {0,0,0,0}, c7 = {0,0,0,0};
    // c_f = fragment f=(g*2+tt); AGPR base = f*16 + kt*4
    MFMA_AB(c0, A0,   0,   3); MFMA_AB(c1, A0,  16,  19); MFMA_AB(c2, A0,  32,  35); MFMA_AB(c3, A0,  48,  51);
    MFMA_AB(c4, A0,  64,  67); MFMA_AB(c5, A0,  80,  83); MFMA_AB(c6, A0,  96,  99); MFMA_AB(c7, A0, 112, 115);
    MFMA_AB(c0, A1,   4,   7); MFMA_AB(c1, A1,  20,  23); MFMA_AB(c2, A1,  36,  39); MFMA_AB(c3, A1,  52,  55);
    MFMA_AB(c4, A1,  68,  71); MFMA_AB(c5, A1,  84,  87); MFMA_AB(c6, A1, 100, 103); MFMA_AB(c7, A1, 116, 119);
    MFMA_AB(c0, A2,   8,  11); MFMA_AB(c1, A2,  24,  27); MFMA_AB(c2, A2,  40,  43); MFMA_AB(c3, A2,  56,  59);
    MFMA_AB(c4, A2,  72,  75); MFMA_AB(c5, A2,  88,  91); MFMA_AB(c6, A2, 104, 107); MFMA_AB(c7, A2, 120, 123);
    MFMA_AB(c0, A3,  12,  15); MFMA_AB(c1, A3,  28,  31); MFMA_AB(c2, A3,  44,  47); MFMA_AB(c3, A3,  60,  63);
    MFMA_AB(c4, A3,  76,  79); MFMA_AB(c5, A3,  92,  95); MFMA_AB(c6, A3, 108, 111); MFMA_AB(c7, A3, 124, 127);
    asm volatile("s_nop 7\n\ts_nop 7\n\ts_nop 7");   // MFMA-D -> VALU read hazard margin
    if (gact) {
      int d0 = tt ? c1.x : c0.x;
      int d1 = tt ? c3.x : c2.x;
      int d2 = tt ? c5.x : c4.x;
      int d3 = tt ? c7.x : c6.x;
      float g0 = (float)d0 * sc0 + bf2f(pu0);
      float g1 = (float)d1 * sc1 + bf2f(pu1);
      float g2 = (float)d2 * sc2 + bf2f(pu2);
      float g3 = (float)d3 * sc3 + bf2f(pu3);
      float f1 = tanh_f(g0), f2 = tanh_f(g1);
      float ti = sigm(g2 * dtc + g3);
      float h = f1 + ti * (f2 - f1);
      int q = (int)rintf(h * 127.f);
      q = q > 127 ? 127 : (q < -127 ? -127 : q);
      hq2[cur ^ 1][j] = (signed char)q;
      hsB[(size_t)cs * 256 + j] = f2bf(h);
      if (cs + 1 < C) {   // prefetch next step (independent of barrier)
        const unsigned short* pn = preB + (size_t)(cs + 1) * 1024;
        pu0 = pn[j]; pu1 = pn[256 + j]; pu2 = pn[512 + j]; pu3 = pn[768 + j];
        dtc = dt[b * SS + s0 + cs + 1] * 10.f;
      }
    }
    cur ^= 1;
    __syncthreads();
  }
  if (tid < 64) hstate[b * 64 + tid] = ((const int*)hq2[cur])[tid];
}

// ---------------------------------------------------------------- k5: head from hseq
__global__ __launch_bounds__(256) void head_kernel(
    const unsigned short* __restrict__ hseq, const float* __restrict__ gW,
    const float* __restrict__ scal, float* __restrict__ out, int s0, int C, int cshift)
{
  int tid = threadIdx.x, wv = tid >> 6, l = tid & 63;
  int row = blockIdx.x * 4 + wv;                 // row in [0, B*C)
  const unsigned short* hr = hseq + (size_t)row * 256 + l * 4;
  ushort4 u = *reinterpret_cast<const ushort4*>(hr);
  float4 gw = *reinterpret_cast<const float4*>(gW + l * 4);
  float v0 = bf2f(u.x), v1 = bf2f(u.y), v2 = bf2f(u.z), v3 = bf2f(u.w);
  float s1 = v0 + v1 + v2 + v3;
  float s2 = v0 * v0 + v1 * v1 + v2 * v2 + v3 * v3;
  float s3 = v0 * gw.x + v1 * gw.y + v2 * gw.z + v3 * gw.w;
  for (int m = 32; m >= 1; m >>= 1) {
    s1 += __shfl_xor(s1, m, 64); s2 += __shfl_xor(s2, m, 64); s3 += __shfl_xor(s3, m, 64);
  }
  if (l == 0) {
    float mean = s1 * (1.f / 256.f);
    float var = s2 * (1.f / 256.f) - mean * mean;
    float inv = rsqrtf(var + 1e-5f);
    int b = row >> cshift, cs = row & (C - 1);
    out[(size_t)b * SS + s0 + cs] = inv * (s3 - mean * scal[0]) + scal[1];
  }
}

// ---------------------------------------------------------------- launch
extern "C" void kernel_launch(void* const* d_in, const int* in_sizes, int n_in,
                              void* d_out, int out_size, void* d_ws, size_t ws_size,
                              hipStream_t stream)
{
  (void)in_sizes; (void)n_in; (void)out_size;
  const float* x        = (const float*)d_in[0];
  const float* dt       = (const float*)d_in[1];
  const float* ln_in_g  = (const float*)d_in[2];
  const float* ln_in_b  = (const float*)d_in[3];
  const float* proj_W   = (const float*)d_in[4];
  const float* proj_b   = (const float*)d_in[5];
  const float* ln_p_g   = (const float*)d_in[6];
  const float* ln_p_b   = (const float*)d_in[7];
  const float* W_ff1    = (const float*)d_in[8];
  const float* b_ff1    = (const float*)d_in[9];
  const float* W_ff2    = (const float*)d_in[10];
  const float* b_ff2    = (const float*)d_in[11];
  const float* W_ta     = (const float*)d_in[12];
  const float* b_ta     = (const float*)d_in[13];
  const float* W_tb     = (const float*)d_in[14];
  const float* b_tb     = (const float*)d_in[15];
  const float* head_g   = (const float*)d_in[16];
  const float* head_b   = (const float*)d_in[17];
  const float* head_W   = (const float*)d_in[18];
  const float* head_bias= (const float*)d_in[19];

  char* ws = (char*)d_ws;
  unsigned short* WxT = (unsigned short*)(ws + OFF_WXT);
  signed char* wq     = (signed char*)(ws + OFF_WQ);
  float* sw           = (float*)(ws + OFF_SW);
  float* bias4        = (float*)(ws + OFF_BIAS4);
  unsigned short* PWT = (unsigned short*)(ws + OFF_PWT);
  float* gWv          = (float*)(ws + OFF_GW);
  float* scal         = (float*)(ws + OFF_SCAL);
  int* hstate         = (int*)(ws + OFF_HST);

  int C = 16;
  for (int c = 2048; c >= 16; c >>= 1) {
    size_t need = OFF_FEAT + (size_t)c * 65536 + (size_t)c * 262144;
    if (need <= ws_size) { C = c; break; }
  }
  unsigned short* featb = (unsigned short*)(ws + OFF_FEAT);   // feat, then hseq
  unsigned short* preb  = (unsigned short*)(ws + OFF_FEAT + (size_t)C * 65536);
  int cshift = 31 - __builtin_clz((unsigned)C);

  prep_kernel<<<2049, 256, 0, stream>>>(proj_W, W_ff1, b_ff1, W_ff2, b_ff2, W_ta, b_ta, W_tb, b_tb,
                                        head_g, head_b, head_W, head_bias,
                                        WxT, wq, sw, bias4, PWT, gWv, scal);
  int nch = SS / C;
  for (int ch = 0; ch < nch; ++ch) {
    int s0 = ch * C;
    feat_kernel<<<dim3(BB * C / 64), 512, 0, stream>>>(x, ln_in_g, ln_in_b, proj_b, ln_p_g, ln_p_b,
                                                       PWT, featb, s0, C, cshift);
    gemm_kernel<<<dim3(BB * C / 128, 8), 256, 0, stream>>>(featb, WxT, bias4, preb);
    scan_kernel<<<dim3(BB), 512, 0, stream>>>(preb, dt, wq, sw, hstate, featb, s0, C);
    head_kernel<<<dim3(BB * C / 4), 256, 0, stream>>>(featb, gWv, scal, (float*)d_out, s0, C, cshift);
  }
}